// Round 11
// baseline (331.145 us; speedup 1.0000x reference)
//
#include <hip/hip_runtime.h>

#define N_NODES 100000
#define N_EDGES 600000
#define N_GRAPHS 64
#define EPS 1e-5f
#define SCAN_BLOCKS 391   // ceil(N_NODES/256)
#define SCAT_BLOCKS 2344  // ceil(N_EDGES/256)

typedef unsigned short u16;
typedef unsigned int u32;
typedef __attribute__((ext_vector_type(8))) short bf16x8;
typedef __attribute__((ext_vector_type(4))) float f32x4;

// ---------- bf16 helpers ----------
__device__ __forceinline__ float bf2f(u16 u) { return __uint_as_float(((u32)u) << 16); }
__device__ __forceinline__ u16 f2bf(float f) {
    u32 u = __float_as_uint(f);
    u += 0x7FFFu + ((u >> 16) & 1u);
    return (u16)(u >> 16);
}
__device__ __forceinline__ float2 bfx2(u32 v) {
    float2 r;
    r.x = __uint_as_float(v << 16);
    r.y = __uint_as_float(v & 0xFFFF0000u);
    return r;
}

// ---------- workspace layout (bytes, 512-aligned) ----------
// zeroed region first
#define WS_COUNTS   ((size_t)0)          // int[N]
#define WS_CURSOR   ((size_t)400384)     // int[N]
#define WS_POOLED   ((size_t)800768)     // u32[64*128] (float bits, >=0)
#define WS_BNSUM    ((size_t)833536)     // float[128]
#define WS_BNSUMSQ  ((size_t)834048)     // float[128]
#define WS_FLAG     ((size_t)834560)     // int (1 = inputs are bf16, 0 = f32)
#define ZERO_BYTES  ((size_t)835072)
// non-zeroed
#define WS_OFFSETS  ((size_t)835072)     // int[N+1]
#define WS_DINV     ((size_t)1235456)    // float[N]
#define WS_DINV2    ((size_t)1635840)    // float[N]; start doubles as scan partials (dead by then)
#define WS_SRCS     ((size_t)2036224)    // int[E]
#define WS_ZF       ((size_t)4436736)    // float[64*64]
#define WS_CANONW   ((size_t)4453120)    // u16[62465] canonical weights (W1-W4 TRANSPOSED)
#define WS_BUFA     ((size_t)4578560)    // 25.6 MB: P2 plane-major [8][N][16] bf16
#define WS_BUFB     ((size_t)30178560)   // 25.6 MB: xs4[4][N][8] -> axs[N][32] (at +6.4MB) -> x2/y3 plane-major [8][N][16]
// total ~53.2 MB (unchanged)

// canonical weight offsets (u16 units); W1..W4 stored transposed [n][k]
#define CW_W1 0
#define CW_B1 4096
#define CW_W2 4224
#define CW_B2 20608
#define CW_W3 20736
#define CW_B3 37120
#define CW_G1 37248
#define CW_BE1 37376
#define CW_W4 37504
#define CW_B4 53888
#define CW_W5 54016
#define CW_B5 62208
#define CW_G2 62272
#define CW_BE2 62336
#define CW_W6 62400
#define CW_B6 62464

// ---------- dtype detector ----------
__global__ void detect_kernel(const u32* __restrict__ xraw, int* __restrict__ flag) {
    __shared__ int cnt;
    if (threadIdx.x == 0) cnt = 0;
    __syncthreads();
    int c = 0;
    for (int i = threadIdx.x; i < 2048; i += 256) {
        u32 w = xraw[i];
        float a = fabsf(__uint_as_float((w & 0xFFFFu) << 16));
        if (a == 0.f || (a > 1e-8f && a < 1e4f)) c++;
    }
    atomicAdd(&cnt, c);
    __syncthreads();
    if (threadIdx.x == 0) *flag = (cnt > 1024) ? 1 : 0;
}

// ---------- canonicalize 16 weight arrays to bf16 (optionally transposed) ----------
struct SmallArgs {
    const void* src[16];
    int n[16];
    int off[16];
    int cols[16];
};
__global__ void convs_kernel(SmallArgs a, u16* __restrict__ dst, const int* __restrict__ flag) {
    int i = blockIdx.x * 256 + threadIdx.x;
    int isbf = *flag;
#pragma unroll
    for (int j = 0; j < 16; j++)
        if (i < a.n[j]) {
            u16 v = isbf ? ((const u16*)a.src[j])[i] : f2bf(((const float*)a.src[j])[i]);
            if (a.cols[j] > 0) {
                int k = i / a.cols[j];
                int n = i - k * a.cols[j];
                int Kd = a.n[j] / a.cols[j];
                dst[a.off[j] + n * Kd + k] = v;
            } else {
                dst[a.off[j] + i] = v;
            }
        }
}

// ---------- degree histogram ----------
__global__ void deg_kernel(const int* __restrict__ dst, int* __restrict__ counts) {
    int e = blockIdx.x * 256 + threadIdx.x;
    if (e < N_EDGES) atomicAdd(&counts[dst[e]], 1);
}

// ---------- hierarchical scan: phase 1 ----------
__global__ __launch_bounds__(256) void reduce_kernel(const int* __restrict__ counts,
                                                     int* __restrict__ partials) {
    int i = blockIdx.x * 256 + threadIdx.x;
    int v = (i < N_NODES) ? counts[i] : 0;
    for (int off = 32; off > 0; off >>= 1) v += __shfl_down(v, off, 64);
    __shared__ int wsum[4];
    if ((threadIdx.x & 63) == 0) wsum[threadIdx.x >> 6] = v;
    __syncthreads();
    if (threadIdx.x == 0) partials[blockIdx.x] = wsum[0] + wsum[1] + wsum[2] + wsum[3];
}

// ---------- phase 2 ----------
__global__ __launch_bounds__(512) void scanpart_kernel(int* __restrict__ partials) {
    __shared__ int sc[512];
    int t = threadIdx.x;
    int v = (t < SCAN_BLOCKS) ? partials[t] : 0;
    sc[t] = v;
    __syncthreads();
    for (int off = 1; off < 512; off <<= 1) {
        int u = (t >= off) ? sc[t - off] : 0;
        __syncthreads();
        sc[t] += u;
        __syncthreads();
    }
    if (t < SCAN_BLOCKS) partials[t] = sc[t] - v;
}

// ---------- phase 3: offsets + dinv ----------
__global__ __launch_bounds__(256) void offsets_kernel(const int* __restrict__ counts,
                                                      const int* __restrict__ partials,
                                                      int* __restrict__ offs,
                                                      float* __restrict__ dinv) {
    int i = blockIdx.x * 256 + threadIdx.x;
    int lane = threadIdx.x & 63, wv = threadIdx.x >> 6;
    int v = (i < N_NODES) ? counts[i] : 0;
    int sv = v;
    for (int off = 1; off < 64; off <<= 1) {
        int u = __shfl_up(sv, off, 64);
        if (lane >= off) sv += u;
    }
    __shared__ int wsum[4];
    if (lane == 63) wsum[wv] = sv;
    __syncthreads();
    int wpre = 0;
    for (int w = 0; w < wv; w++) wpre += wsum[w];
    int excl = sv - v + wpre + partials[blockIdx.x];
    if (i < N_NODES) {
        offs[i] = excl;
        dinv[i] = rsqrtf((float)(v + 1));
    }
    if (i == N_NODES - 1) offs[N_NODES] = excl + v;
}

// ---------- merged: scatter edges into CSR + canonicalize x (plane-major, *dinv) ----------
__global__ void scatconv_kernel(const int* __restrict__ src, const int* __restrict__ dst,
                                const int* __restrict__ offs, int* __restrict__ cursor,
                                int* __restrict__ srcs, const void* __restrict__ xsrc,
                                u16* __restrict__ xs4, const int* __restrict__ flag,
                                const float* __restrict__ dinv) {
    int b = blockIdx.x;
    if (b < SCAT_BLOCKS) {
        int e = b * 256 + threadIdx.x;
        if (e < N_EDGES) {
            int d = dst[e];
            int p = offs[d] + atomicAdd(&cursor[d], 1);
            srcs[p] = src[e];
        }
    } else {
        int i = (b - SCAT_BLOCKS) * 256 + threadIdx.x;
        if (i < N_NODES * 32) {
            int r = i >> 5, c = i & 31;
            float v = (*flag) ? bf2f(((const u16*)xsrc)[i]) : ((const float*)xsrc)[i];
            xs4[(size_t)(c >> 3) * (N_NODES * 8) + (size_t)r * 8 + (c & 7)] =
                f2bf(v * dinv[r]);
        }
    }
}

// ---------- agg1: XCD-sliced conv1 aggregation in x-space (K=32, 4 planes) ----------
__global__ __launch_bounds__(256, 4) void agg1_kernel(const u16* __restrict__ xs4,
                                                      const int* __restrict__ offs,
                                                      const int* __restrict__ srcs,
                                                      const float* __restrict__ dinv,
                                                      u16* __restrict__ axs) {
    const int p = blockIdx.x & 3;
    const int r = (blockIdx.x >> 2) * 256 + threadIdx.x;
    if (r >= N_NODES) return;
    const u16* base = xs4 + (size_t)p * (N_NODES * 8);
    float acc[8];
    {
        uint4 own = *(const uint4*)(base + (size_t)r * 8);
        u32 w4[4] = {own.x, own.y, own.z, own.w};
#pragma unroll
        for (int t = 0; t < 4; t++) {
            float2 f = bfx2(w4[t]);
            acc[2 * t] = f.x;
            acc[2 * t + 1] = f.y;
        }
    }
    const int e0 = offs[r], e1 = offs[r + 1];
    for (int e = e0; e < e1; e += 4) {
        int ss[4];
        float mm[4];
        ss[0] = srcs[e];
        mm[0] = 1.f;
#pragma unroll
        for (int j = 1; j < 4; j++) {
            ss[j] = srcs[min(e + j, e1 - 1)];
            mm[j] = (e + j < e1) ? 1.f : 0.f;
        }
        uint4 rr[4];
#pragma unroll
        for (int j = 0; j < 4; j++) rr[j] = *(const uint4*)(base + (size_t)ss[j] * 8);
#pragma unroll
        for (int j = 0; j < 4; j++) {
            u32 w4[4] = {rr[j].x, rr[j].y, rr[j].z, rr[j].w};
#pragma unroll
            for (int t = 0; t < 4; t++) {
                float2 f = bfx2(w4[t]);
                acc[2 * t] = fmaf(f.x, mm[j], acc[2 * t]);
                acc[2 * t + 1] = fmaf(f.y, mm[j], acc[2 * t + 1]);
            }
        }
    }
    const float di = dinv[r];
    uint4 outv;
    u32* pk = (u32*)&outv;
#pragma unroll
    for (int t = 0; t < 4; t++)
        pk[t] = (u32)f2bf(acc[2 * t] * di) | ((u32)f2bf(acc[2 * t + 1] * di) << 16);
    *(uint4*)(axs + (size_t)r * 32 + p * 8) = outv;
}

// ---------- agg2: XCD-sliced conv2 aggregation (K=128, 8 planes) ----------
__global__ __launch_bounds__(256, 4) void agg2_kernel(const u16* __restrict__ P2,
                                                      const int* __restrict__ offs,
                                                      const int* __restrict__ srcs,
                                                      const float* __restrict__ dinv,
                                                      const u16* __restrict__ b2,
                                                      u16* __restrict__ x2p) {
    const int p = blockIdx.x & 7;
    const int t = threadIdx.x;
    const int r = (blockIdx.x >> 3) * 128 + (t >> 1);
    const int half = t & 1;
    if (r >= N_NODES) return;
    const u16* base = P2 + (size_t)p * (N_NODES * 16) + half * 8;
    float acc[8];
    {
        uint4 own = *(const uint4*)(base + (size_t)r * 16);
        u32 w4[4] = {own.x, own.y, own.z, own.w};
#pragma unroll
        for (int j = 0; j < 4; j++) {
            float2 f = bfx2(w4[j]);
            acc[2 * j] = f.x;
            acc[2 * j + 1] = f.y;
        }
    }
    const int e0 = offs[r], e1 = offs[r + 1];
    for (int e = e0; e < e1; e += 4) {
        int ss[4];
        float mm[4];
        ss[0] = srcs[e];
        mm[0] = 1.f;
#pragma unroll
        for (int j = 1; j < 4; j++) {
            ss[j] = srcs[min(e + j, e1 - 1)];
            mm[j] = (e + j < e1) ? 1.f : 0.f;
        }
        uint4 rr[4];
#pragma unroll
        for (int j = 0; j < 4; j++) rr[j] = *(const uint4*)(base + (size_t)ss[j] * 16);
#pragma unroll
        for (int j = 0; j < 4; j++) {
            u32 w4[4] = {rr[j].x, rr[j].y, rr[j].z, rr[j].w};
#pragma unroll
            for (int k = 0; k < 4; k++) {
                float2 f = bfx2(w4[k]);
                acc[2 * k] = fmaf(f.x, mm[j], acc[2 * k]);
                acc[2 * k + 1] = fmaf(f.y, mm[j], acc[2 * k + 1]);
            }
        }
    }
    const float di = dinv[r];
    uint4 bb = *(const uint4*)(b2 + p * 16 + half * 8);
    u32 bw[4] = {bb.x, bb.y, bb.z, bb.w};
    uint4 outv;
    u32* pk = (u32*)&outv;
#pragma unroll
    for (int j = 0; j < 4; j++) {
        float2 fb = bfx2(bw[j]);
        float vx = fmaxf(fmaf(acc[2 * j], di, fb.x), 0.f);
        float vy = fmaxf(fmaf(acc[2 * j + 1], di, fb.y), 0.f);
        pk[j] = (u32)f2bf(vx) | ((u32)f2bf(vy) << 16);
    }
    *(uint4*)(x2p + (size_t)p * (N_NODES * 16) + (size_t)r * 16 + half * 8) = outv;
}

// ---------- gemmx: chained W1/W2 GEMMs (round-6 proven: LDS-staged W) ----------
__global__ __launch_bounds__(256, 3) void gemmx_kernel(
    const u16* __restrict__ axs, const u16* __restrict__ W1t, const u16* __restrict__ b1,
    const u16* __restrict__ W2t, u16* __restrict__ P2, const float* __restrict__ dinv, int M) {
    __shared__ __align__(16) u16 ldsA[128 * 40];   // W1t staged; later 4x per-wave [32][40] tbuf
    __shared__ __align__(16) u16 ldsB[128 * 136];  // W2t staged

    const int tid = threadIdx.x;
    const int wave = tid >> 6;
    const int lane = tid & 63;
    const int l15 = lane & 15;
    const int quad = lane >> 4;
    const int row0 = blockIdx.x * 128 + wave * 32;

    {  // stage W1t [128][32] -> ldsA [128][40]
        const u32* g = (const u32*)W1t;
        u32* l = (u32*)ldsA;
        for (int i = tid; i < 128 * 16; i += 256) {
            int n = i >> 4, j = i & 15;
            l[n * 20 + j] = g[i];
        }
    }
    {  // stage W2t [128][128] -> ldsB [128][136]
        const u32* g = (const u32*)W2t;
        u32* l = (u32*)ldsB;
        for (int i = tid; i < 128 * 64; i += 256) {
            int n = i >> 6, j = i & 63;
            l[n * 68 + j] = g[i];
        }
    }

    uint4 gr1[2];
#pragma unroll
    for (int rt = 0; rt < 2; rt++) {
        int r = min(row0 + rt * 16 + l15, M - 1);
        gr1[rt] = *(const uint4*)(axs + (size_t)r * 32 + quad * 8);
    }
    __syncthreads();

    f32x4 acc1[2][8];
#pragma unroll
    for (int rt = 0; rt < 2; rt++)
#pragma unroll
        for (int nt = 0; nt < 8; nt++) acc1[rt][nt] = {0.f, 0.f, 0.f, 0.f};
#pragma unroll
    for (int nt = 0; nt < 8; nt++) {
        bf16x8 bf = *(const bf16x8*)&ldsA[(nt * 16 + l15) * 40 + quad * 8];
        acc1[0][nt] = __builtin_amdgcn_mfma_f32_16x16x32_bf16(
            __builtin_bit_cast(bf16x8, gr1[0]), bf, acc1[0][nt], 0, 0, 0);
        acc1[1][nt] = __builtin_amdgcn_mfma_f32_16x16x32_bf16(
            __builtin_bit_cast(bf16x8, gr1[1]), bf, acc1[1][nt], 0, 0, 0);
    }
    __syncthreads();  // all waves done with ldsA -> safe to reuse as tbuf

    float bcol[8];
#pragma unroll
    for (int nt = 0; nt < 8; nt++) bcol[nt] = bf2f(b1[nt * 16 + l15]);
    u16* tb = ldsA + wave * 1280;  // per-wave [32][40]
    uint4 gr2[2][4];
#pragma unroll
    for (int kt = 0; kt < 4; kt++) {
#pragma unroll
        for (int rt = 0; rt < 2; rt++)
#pragma unroll
            for (int c2 = 0; c2 < 2; c2++) {
                int nt = 2 * kt + c2;
#pragma unroll
                for (int i = 0; i < 4; i++) {
                    float v = fmaxf(acc1[rt][nt][i] + bcol[nt], 0.f);
                    tb[(rt * 16 + quad * 4 + i) * 40 + c2 * 16 + l15] = f2bf(v);
                }
            }
#pragma unroll
        for (int rt = 0; rt < 2; rt++)
            gr2[rt][kt] = *(const uint4*)&tb[(rt * 16 + l15) * 40 + quad * 8];
    }

    f32x4 acc2[2][8];
#pragma unroll
    for (int rt = 0; rt < 2; rt++)
#pragma unroll
        for (int nt = 0; nt < 8; nt++) acc2[rt][nt] = {0.f, 0.f, 0.f, 0.f};
#pragma unroll
    for (int kt = 0; kt < 4; kt++) {
#pragma unroll
        for (int nt = 0; nt < 8; nt++) {
            bf16x8 bf = *(const bf16x8*)&ldsB[(nt * 16 + l15) * 136 + kt * 32 + quad * 8];
            acc2[0][nt] = __builtin_amdgcn_mfma_f32_16x16x32_bf16(
                __builtin_bit_cast(bf16x8, gr2[0][kt]), bf, acc2[0][nt], 0, 0, 0);
            acc2[1][nt] = __builtin_amdgcn_mfma_f32_16x16x32_bf16(
                __builtin_bit_cast(bf16x8, gr2[1][kt]), bf, acc2[1][nt], 0, 0, 0);
        }
    }

#pragma unroll
    for (int rt = 0; rt < 2; rt++)
#pragma unroll
        for (int i = 0; i < 4; i++) {
            int r = row0 + rt * 16 + quad * 4 + i;
            if (r < M) {
                float ds = dinv[r];
#pragma unroll
                for (int nt = 0; nt < 8; nt++)
                    P2[(size_t)nt * (N_NODES * 16) + (size_t)r * 16 + l15] =
                        f2bf(acc2[rt][nt][i] * ds);
            }
        }
}

// ---------- gemm3: y3 = x2 @ W3 + b3 (+BN stats), SWAPPED operands, SPLIT-M ----------
// Round-11: 64-row blocks (wave = ONE 16-row tile), grid 1563 -> 4 blocks/CU resident
// (LDS-capped) vs 3 grid-supplied before; A-rows still read exactly once (unlike split-N).
// W staged via uint4 loads + b128 LDS writes (8 iters/thread, row stride 272B = 17x16B).
__global__ __launch_bounds__(256, 4) void gemm3_kernel(
    const u16* __restrict__ A, const u16* __restrict__ Wt, const u16* __restrict__ bias,
    u16* __restrict__ C, float* __restrict__ bn_sum, float* __restrict__ bn_sumsq, int M) {
    constexpr int KP = 136;
    __shared__ __align__(16) u16 Wl[128 * KP];
    __shared__ float csum[128], csumsq[128];

    const int tid = threadIdx.x;
    const int wave = tid >> 6;
    const int lane = tid & 63;
    const int l15 = lane & 15;
    const int quad = lane >> 4;
    const int row0 = blockIdx.x * 64 + wave * 16;

    // prefetch A fragments from plane-major layout: 4 x 16B in flight while W stages
    uint4 ra[4];
    const int nd = row0 + l15;
    {
        int r = min(nd, M - 1);
#pragma unroll
        for (int kt = 0; kt < 4; kt++) {
            int plane = 2 * kt + (quad >> 1);
            ra[kt] = *(const uint4*)(A + (size_t)plane * (N_NODES * 16) + (size_t)r * 16 +
                                     (quad & 1) * 8);
        }
    }

    {  // stage W3t [128][128] -> Wl [128][136] via uint4 (8 iters/thread)
        const uint4* g = (const uint4*)Wt;
        uint4* l = (uint4*)Wl;  // row stride 17 uint4 (= 272 B, 16B-aligned)
        for (int i = tid; i < 128 * 16; i += 256) {
            int n = i >> 4, j = i & 15;
            l[n * 17 + j] = g[i];
        }
    }
    if (tid < 128) {
        csum[tid] = 0.f;
        csumsq[tid] = 0.f;
    }
    __syncthreads();

    f32x4 acc[8];
#pragma unroll
    for (int nt = 0; nt < 8; nt++) acc[nt] = {0.f, 0.f, 0.f, 0.f};

#pragma unroll
    for (int kt = 0; kt < 4; kt++) {
        bf16x8 a0 = __builtin_bit_cast(bf16x8, ra[kt]);
#pragma unroll
        for (int nt = 0; nt < 8; nt++) {
            bf16x8 wf = *(const bf16x8*)&Wl[(nt * 16 + l15) * KP + kt * 32 + quad * 8];
            acc[nt] = __builtin_amdgcn_mfma_f32_16x16x32_bf16(wf, a0, acc[nt], 0, 0, 0);
        }
    }

    // epilogue: per nt -> bias, plane-major uint2 store, stats reduce
    const bool ok = nd < M;
#pragma unroll
    for (int nt = 0; nt < 8; nt++) {
        uint2 braw = *(const uint2*)(bias + nt * 16 + quad * 4);
        float2 f0 = bfx2(braw.x), f1 = bfx2(braw.y);
        float bb[4] = {f0.x, f0.y, f1.x, f1.y};
        float v0[4];
#pragma unroll
        for (int i = 0; i < 4; i++) v0[i] = ok ? (acc[nt][i] + bb[i]) : 0.f;
        if (ok) {
            uint2 st;
            st.x = (u32)f2bf(v0[0]) | ((u32)f2bf(v0[1]) << 16);
            st.y = (u32)f2bf(v0[2]) | ((u32)f2bf(v0[3]) << 16);
            *(uint2*)(C + (size_t)nt * (N_NODES * 16) + (size_t)nd * 16 + quad * 4) = st;
        }
        // stats: reduce over the 16-lane node group (l15 bits)
#pragma unroll
        for (int i = 0; i < 4; i++) {
            float s = v0[i];
            float q = v0[i] * v0[i];
#pragma unroll
            for (int m = 1; m < 16; m <<= 1) {
                s += __shfl_xor(s, m);
                q += __shfl_xor(q, m);
            }
            if (l15 == 0) {
                atomicAdd(&csum[nt * 16 + quad * 4 + i], s);
                atomicAdd(&csumsq[nt * 16 + quad * 4 + i], q);
            }
        }
    }
    __syncthreads();
    if (tid < 128) {
        atomicAdd(&bn_sum[tid], csum[tid]);
        atomicAdd(&bn_sumsq[tid], csumsq[tid]);
    }
}

// ---------- gemm4: relu(relu(BN(y3)) @ W4 + b4) -> segment max, SPLIT-M + inline BN ----------
// 64-row blocks (wave = one 16-row tile); W4 staged via uint4; bnstats folded in.
__global__ __launch_bounds__(256, 4) void gemm4_kernel(
    const u16* __restrict__ A, const u16* __restrict__ Wt, const u16* __restrict__ bias,
    const float* __restrict__ bn_sum, const float* __restrict__ bn_sumsq,
    const u16* __restrict__ g1, const u16* __restrict__ be1, const int* __restrict__ batch,
    u32* __restrict__ pooled, int M) {
    constexpr int KP = 136;
    __shared__ __align__(16) u16 Wl[128 * KP];
    __shared__ u32 lmax[4 * 128];
    __shared__ float sscale[128], sshift[128];

    const int tid = threadIdx.x;
    const int wave = tid >> 6;
    const int lane = tid & 63;
    const int l15 = lane & 15;
    const int quad = lane >> 4;
    const int row0 = blockIdx.x * 64 + wave * 16;

    // prefetch raw A fragments (plane-major)
    uint4 ra[4];
    {
        int r = min(row0 + l15, M - 1);
#pragma unroll
        for (int kt = 0; kt < 4; kt++) {
            int plane = 2 * kt + (quad >> 1);
            ra[kt] = *(const uint4*)(A + (size_t)plane * (N_NODES * 16) + (size_t)r * 16 +
                                     (quad & 1) * 8);
        }
    }

    {  // stage W4t via uint4
        const uint4* g = (const uint4*)Wt;
        uint4* l = (uint4*)Wl;
        for (int i = tid; i < 128 * 16; i += 256) {
            int n = i >> 4, j = i & 15;
            l[n * 17 + j] = g[i];
        }
    }
    for (int i = tid; i < 512; i += 256) lmax[i] = 0u;
    if (tid < 128) {  // inline bnstats: raw sums -> scale/shift
        float mu = bn_sum[tid] / (float)N_NODES;
        float var = bn_sumsq[tid] / (float)N_NODES - mu * mu;
        float rstd = rsqrtf(var + EPS);
        float sc = rstd * bf2f(g1[tid]);
        sscale[tid] = sc;
        sshift[tid] = bf2f(be1[tid]) - mu * sc;
    }

    const int base = blockIdx.x * 64;
    const int gfirst = batch[min(base, M - 1)];
    const int glast = batch[min(base + 63, M - 1)];
    const bool fast = (glast - gfirst) < 4;
    __syncthreads();

    f32x4 acc[8];
#pragma unroll
    for (int nt = 0; nt < 8; nt++) acc[nt] = {0.f, 0.f, 0.f, 0.f};

#pragma unroll
    for (int kt = 0; kt < 4; kt++) {
        float s8[8], h8[8];
#pragma unroll
        for (int t = 0; t < 8; t++) {
            s8[t] = sscale[kt * 32 + quad * 8 + t];
            h8[t] = sshift[kt * 32 + quad * 8 + t];
        }
        bf16x8 af;
        {
            u32 w4[4] = {ra[kt].x, ra[kt].y, ra[kt].z, ra[kt].w};
            bf16x8 tmp;
#pragma unroll
            for (int t = 0; t < 4; t++) {
                float2 f = bfx2(w4[t]);
                f.x = fmaxf(fmaf(f.x, s8[2 * t], h8[2 * t]), 0.f);
                f.y = fmaxf(fmaf(f.y, s8[2 * t + 1], h8[2 * t + 1]), 0.f);
                tmp[2 * t] = (short)f2bf(f.x);
                tmp[2 * t + 1] = (short)f2bf(f.y);
            }
            af = tmp;
        }
#pragma unroll
        for (int nt = 0; nt < 8; nt++) {
            bf16x8 bf = *(const bf16x8*)&Wl[(nt * 16 + l15) * KP + kt * 32 + quad * 8];
            acc[nt] = __builtin_amdgcn_mfma_f32_16x16x32_bf16(af, bf, acc[nt], 0, 0, 0);
        }
    }

    float b[8];
#pragma unroll
    for (int nt = 0; nt < 8; nt++) b[nt] = bf2f(bias[nt * 16 + l15]);
    float cur[8];
#pragma unroll
    for (int nt = 0; nt < 8; nt++) cur[nt] = 0.f;
    int curg = -1;
#pragma unroll
    for (int i = 0; i < 4; i++) {
        int r = row0 + quad * 4 + i;
        if (r < M) {
            int g = batch[r];
            if (g != curg) {
                if (curg >= 0) {
#pragma unroll
                    for (int nt = 0; nt < 8; nt++)
                        if (cur[nt] > 0.f) {
                            u32 bits = __float_as_uint(cur[nt]);
                            if (fast)
                                atomicMax(&lmax[(curg - gfirst) * 128 + nt * 16 + l15], bits);
                            else
                                atomicMax(&pooled[curg * 128 + nt * 16 + l15], bits);
                        }
                }
                curg = g;
#pragma unroll
                for (int nt = 0; nt < 8; nt++) cur[nt] = 0.f;
            }
#pragma unroll
            for (int nt = 0; nt < 8; nt++)
                cur[nt] = fmaxf(cur[nt], fmaxf(acc[nt][i] + b[nt], 0.f));
        }
    }
    if (curg >= 0) {
#pragma unroll
        for (int nt = 0; nt < 8; nt++)
            if (cur[nt] > 0.f) {
                u32 bits = __float_as_uint(cur[nt]);
                if (fast)
                    atomicMax(&lmax[(curg - gfirst) * 128 + nt * 16 + l15], bits);
                else
                    atomicMax(&pooled[curg * 128 + nt * 16 + l15], bits);
            }
    }
    __syncthreads();
    if (fast) {
        int ngr = glast - gfirst + 1;
        for (int i = tid; i < ngr * 128; i += 256) {
            u32 v = lmax[i];
            if (v) atomicMax(&pooled[gfirst * 128 + i], v);
        }
    }
}

// ---------- head part 1: zf[64,64] = pooled[64,128] @ W5 + b5 ----------
__global__ __launch_bounds__(256) void head1_kernel(const u32* __restrict__ pooled,
                                                    const u16* __restrict__ W5,
                                                    const u16* __restrict__ b5,
                                                    float* __restrict__ zf) {
    __shared__ float red[4][64];
    int g = blockIdx.x;
    int c = threadIdx.x & 63;
    int kq = threadIdx.x >> 6;
    const u32* prow = pooled + g * 128;
    float p = 0.f;
    for (int k = kq * 32; k < kq * 32 + 32; k++)
        p = fmaf(__uint_as_float(prow[k]), bf2f(W5[k * 64 + c]), p);
    red[kq][c] = p;
    __syncthreads();
    if (kq == 0) zf[g * 64 + c] = red[0][c] + red[1][c] + red[2][c] + red[3][c] + bf2f(b5[c]);
}

// ---------- head part 2 ----------
__global__ __launch_bounds__(64) void head2_kernel(const float* __restrict__ zf,
                                                   const u16* __restrict__ g2,
                                                   const u16* __restrict__ be2,
                                                   const u16* __restrict__ W6,
                                                   const u16* __restrict__ b6,
                                                   void* __restrict__ outv,
                                                   const int* __restrict__ flag) {
    __shared__ float Z[64][65];
    __shared__ float sc[64], sh[64], w6[64];
    int t = threadIdx.x;
    for (int idx = t; idx < 4096; idx += 64) Z[idx >> 6][idx & 63] = zf[idx];
    w6[t] = bf2f(W6[t]);
    __syncthreads();
    {
        float s = 0.f, sq = 0.f;
        for (int g = 0; g < 64; g++) {
            float v = Z[g][t];
            s += v;
            sq += v * v;
        }
        float mu = s * (1.f / 64.f);
        float var = sq * (1.f / 64.f) - mu * mu;
        float rstd = rsqrtf(var + EPS);
        float scale = rstd * bf2f(g2[t]);
        sc[t] = scale;
        sh[t] = bf2f(be2[t]) - mu * scale;
    }
    __syncthreads();
    float o = 0.f;
    for (int c = 0; c < 64; c++)
        o = fmaf(fmaxf(fmaf(Z[t][c], sc[c], sh[c]), 0.f), w6[c], o);
    float res = o + bf2f(b6[0]);
    if (*flag)
        ((u16*)outv)[t] = f2bf(res);
    else
        ((float*)outv)[t] = res;
}

extern "C" void kernel_launch(void* const* d_in, const int* in_sizes, int n_in, void* d_out,
                              int out_size, void* d_ws, size_t ws_size, hipStream_t stream) {
    const void* x = d_in[0];
    const int* ei = (const int*)d_in[1];
    const int* bat = (const int*)d_in[2];

    char* ws = (char*)d_ws;
    int* counts = (int*)(ws + WS_COUNTS);
    int* cursor = (int*)(ws + WS_CURSOR);
    u32* pooled = (u32*)(ws + WS_POOLED);
    float* bnsum = (float*)(ws + WS_BNSUM);
    float* bnssq = (float*)(ws + WS_BNSUMSQ);
    int* flag = (int*)(ws + WS_FLAG);
    int* offs = (int*)(ws + WS_OFFSETS);
    float* dinv = (float*)(ws + WS_DINV);
    int* partials = (int*)(ws + WS_DINV2);
    int* srcs = (int*)(ws + WS_SRCS);
    float* zf = (float*)(ws + WS_ZF);
    u16* cw = (u16*)(ws + WS_CANONW);
    u16* P2 = (u16*)(ws + WS_BUFA);             // plane-major hs2 [8][N][16]
    u16* xs4 = (u16*)(ws + WS_BUFB);            // plane-major xs [4][N][8] (dead after agg1)
    u16* axs = (u16*)(ws + WS_BUFB) + 3200000;  // [N][32] at BUFB+6.4MB (dead after gemmx)
    u16* x2p = (u16*)(ws + WS_BUFB);            // plane-major x2/y3 [8][N][16], in-place reuse

    const int* esrc = ei;
    const int* edst = ei + N_EDGES;

    hipMemsetAsync(ws, 0, ZERO_BYTES, stream);
    detect_kernel<<<1, 256, 0, stream>>>((const u32*)x, flag);

    SmallArgs sa;
    const int cw_off[16] = {CW_W1, CW_B1, CW_W2, CW_B2, CW_W3, CW_B3, CW_G1, CW_BE1,
                            CW_W4, CW_B4, CW_W5, CW_B5, CW_G2, CW_BE2, CW_W6, CW_B6};
    const int cw_n[16] = {4096, 128, 16384, 128, 16384, 128, 128, 128,
                          16384, 128, 8192, 64, 64, 64, 64, 1};
    const int cw_c[16] = {128, 0, 128, 0, 128, 0, 0, 0, 128, 0, 0, 0, 0, 0, 0, 0};
    for (int j = 0; j < 16; j++) {
        sa.src[j] = d_in[3 + j];
        sa.n[j] = cw_n[j];
        sa.off[j] = cw_off[j];
        sa.cols[j] = cw_c[j];
    }
    convs_kernel<<<64, 256, 0, stream>>>(sa, cw, flag);

    deg_kernel<<<(N_EDGES + 255) / 256, 256, 0, stream>>>(edst, counts);
    reduce_kernel<<<SCAN_BLOCKS, 256, 0, stream>>>(counts, partials);
    scanpart_kernel<<<1, 512, 0, stream>>>(partials);
    offsets_kernel<<<SCAN_BLOCKS, 256, 0, stream>>>(counts, partials, offs, dinv);
    // merged scatter + convx (both depend only on offsets)
    scatconv_kernel<<<SCAT_BLOCKS + (N_NODES * 32 + 255) / 256, 256, 0, stream>>>(
        esrc, edst, offs, cursor, srcs, x, xs4, flag, dinv);

    const int gb = (N_NODES + 127) / 128;
    const int gb64 = (N_NODES + 63) / 64;
    // agg1: axs = aggnorm(xs) (XCD-sliced gather, K=32)
    agg1_kernel<<<4 * SCAN_BLOCKS, 256, 0, stream>>>(xs4, offs, srcs, dinv, axs);
    // gemmx: x1 = relu(axs@W1 + b1); hs2 = (x1@W2)*dinv -> P2 plane-major
    gemmx_kernel<<<gb, 256, 0, stream>>>(axs, cw + CW_W1, cw + CW_B1, cw + CW_W2, P2, dinv,
                                         N_NODES);
    // agg2: x2 = relu((agg hs2 + hs2)*dinv + b2) (XCD-sliced gather) -> x2p plane-major
    agg2_kernel<<<8 * gb, 256, 0, stream>>>(P2, offs, srcs, dinv, cw + CW_B2, x2p);
    // gemm3 (split-M, 64-row blocks): y3 = x2 @ W3 + b3 (+BN stats) -> in place over x2p
    gemm3_kernel<<<gb64, 256, 0, stream>>>(x2p, cw + CW_W3, cw + CW_B3, x2p, bnsum, bnssq,
                                           N_NODES);
    // gemm4 (split-M + inline bnstats): relu(relu(BN(y3)) @ W4 + b4) -> segment max -> pooled
    gemm4_kernel<<<gb64, 256, 0, stream>>>(x2p, cw + CW_W4, cw + CW_B4, bnsum, bnssq,
                                           cw + CW_G1, cw + CW_BE1, bat, pooled, N_NODES);
    // head
    head1_kernel<<<N_GRAPHS, 256, 0, stream>>>(pooled, cw + CW_W5, cw + CW_B5, zf);
    head2_kernel<<<1, 64, 0, stream>>>(zf, cw + CW_G2, cw + CW_BE2, cw + CW_W6, cw + CW_B6,
                                       d_out, flag);
}

// Round 12
// 313.413 us; speedup vs baseline: 1.0566x; 1.0566x over previous
//
#include <hip/hip_runtime.h>

#define N_NODES 100000
#define N_EDGES 600000
#define N_GRAPHS 64
#define EPS 1e-5f
#define SCAN_BLOCKS 391   // ceil(N_NODES/256)
#define SCAT_BLOCKS 2344  // ceil(N_EDGES/256)

typedef unsigned short u16;
typedef unsigned int u32;
typedef __attribute__((ext_vector_type(8))) short bf16x8;
typedef __attribute__((ext_vector_type(4))) float f32x4;

// ---------- bf16 helpers ----------
__device__ __forceinline__ float bf2f(u16 u) { return __uint_as_float(((u32)u) << 16); }
__device__ __forceinline__ u16 f2bf(float f) {
    u32 u = __float_as_uint(f);
    u += 0x7FFFu + ((u >> 16) & 1u);
    return (u16)(u >> 16);
}
__device__ __forceinline__ float2 bfx2(u32 v) {
    float2 r;
    r.x = __uint_as_float(v << 16);
    r.y = __uint_as_float(v & 0xFFFF0000u);
    return r;
}

// ---------- workspace layout (bytes, 512-aligned) ----------
// zeroed region first
#define WS_COUNTS   ((size_t)0)          // int[N]
#define WS_CURSOR   ((size_t)400384)     // int[N]
#define WS_POOLED   ((size_t)800768)     // u32[64*128] (float bits, >=0)
#define WS_BNSUM    ((size_t)833536)     // float[128]
#define WS_BNSUMSQ  ((size_t)834048)     // float[128]
#define WS_FLAG     ((size_t)834560)     // int (1 = inputs are bf16, 0 = f32)
#define ZERO_BYTES  ((size_t)835072)
// non-zeroed
#define WS_OFFSETS  ((size_t)835072)     // int[N+1]
#define WS_DINV     ((size_t)1235456)    // float[N]
#define WS_DINV2    ((size_t)1635840)    // float[N]; start doubles as scan partials (dead by then)
#define WS_SRCS     ((size_t)2036224)    // int[E]
#define WS_ZF       ((size_t)4436736)    // float[64*64]
#define WS_CANONW   ((size_t)4453120)    // u16[62465] canonical weights (W1-W4 TRANSPOSED)
#define WS_BUFA     ((size_t)4578560)    // 25.6 MB: P2 plane-major [8][N][16] bf16
#define WS_BUFB     ((size_t)30178560)   // 25.6 MB: xs4[4][N][8] -> axs[N][32] (at +6.4MB) -> x2/y3 plane-major [8][N][16]
// total ~53.2 MB (unchanged)

// canonical weight offsets (u16 units); W1..W4 stored transposed [n][k]
#define CW_W1 0
#define CW_B1 4096
#define CW_W2 4224
#define CW_B2 20608
#define CW_W3 20736
#define CW_B3 37120
#define CW_G1 37248
#define CW_BE1 37376
#define CW_W4 37504
#define CW_B4 53888
#define CW_W5 54016
#define CW_B5 62208
#define CW_G2 62272
#define CW_BE2 62336
#define CW_W6 62400
#define CW_B6 62464

// ---------- dtype detector ----------
__global__ void detect_kernel(const u32* __restrict__ xraw, int* __restrict__ flag) {
    __shared__ int cnt;
    if (threadIdx.x == 0) cnt = 0;
    __syncthreads();
    int c = 0;
    for (int i = threadIdx.x; i < 2048; i += 256) {
        u32 w = xraw[i];
        float a = fabsf(__uint_as_float((w & 0xFFFFu) << 16));
        if (a == 0.f || (a > 1e-8f && a < 1e4f)) c++;
    }
    atomicAdd(&cnt, c);
    __syncthreads();
    if (threadIdx.x == 0) *flag = (cnt > 1024) ? 1 : 0;
}

// ---------- canonicalize 16 weight arrays to bf16 (optionally transposed) ----------
struct SmallArgs {
    const void* src[16];
    int n[16];
    int off[16];
    int cols[16];
};
__global__ void convs_kernel(SmallArgs a, u16* __restrict__ dst, const int* __restrict__ flag) {
    int i = blockIdx.x * 256 + threadIdx.x;
    int isbf = *flag;
#pragma unroll
    for (int j = 0; j < 16; j++)
        if (i < a.n[j]) {
            u16 v = isbf ? ((const u16*)a.src[j])[i] : f2bf(((const float*)a.src[j])[i]);
            if (a.cols[j] > 0) {
                int k = i / a.cols[j];
                int n = i - k * a.cols[j];
                int Kd = a.n[j] / a.cols[j];
                dst[a.off[j] + n * Kd + k] = v;
            } else {
                dst[a.off[j] + i] = v;
            }
        }
}

// ---------- degree histogram ----------
__global__ void deg_kernel(const int* __restrict__ dst, int* __restrict__ counts) {
    int e = blockIdx.x * 256 + threadIdx.x;
    if (e < N_EDGES) atomicAdd(&counts[dst[e]], 1);
}

// ---------- hierarchical scan: phase 1 ----------
__global__ __launch_bounds__(256) void reduce_kernel(const int* __restrict__ counts,
                                                     int* __restrict__ partials) {
    int i = blockIdx.x * 256 + threadIdx.x;
    int v = (i < N_NODES) ? counts[i] : 0;
    for (int off = 32; off > 0; off >>= 1) v += __shfl_down(v, off, 64);
    __shared__ int wsum[4];
    if ((threadIdx.x & 63) == 0) wsum[threadIdx.x >> 6] = v;
    __syncthreads();
    if (threadIdx.x == 0) partials[blockIdx.x] = wsum[0] + wsum[1] + wsum[2] + wsum[3];
}

// ---------- phase 2 ----------
__global__ __launch_bounds__(512) void scanpart_kernel(int* __restrict__ partials) {
    __shared__ int sc[512];
    int t = threadIdx.x;
    int v = (t < SCAN_BLOCKS) ? partials[t] : 0;
    sc[t] = v;
    __syncthreads();
    for (int off = 1; off < 512; off <<= 1) {
        int u = (t >= off) ? sc[t - off] : 0;
        __syncthreads();
        sc[t] += u;
        __syncthreads();
    }
    if (t < SCAN_BLOCKS) partials[t] = sc[t] - v;
}

// ---------- phase 3: offsets + dinv ----------
__global__ __launch_bounds__(256) void offsets_kernel(const int* __restrict__ counts,
                                                      const int* __restrict__ partials,
                                                      int* __restrict__ offs,
                                                      float* __restrict__ dinv) {
    int i = blockIdx.x * 256 + threadIdx.x;
    int lane = threadIdx.x & 63, wv = threadIdx.x >> 6;
    int v = (i < N_NODES) ? counts[i] : 0;
    int sv = v;
    for (int off = 1; off < 64; off <<= 1) {
        int u = __shfl_up(sv, off, 64);
        if (lane >= off) sv += u;
    }
    __shared__ int wsum[4];
    if (lane == 63) wsum[wv] = sv;
    __syncthreads();
    int wpre = 0;
    for (int w = 0; w < wv; w++) wpre += wsum[w];
    int excl = sv - v + wpre + partials[blockIdx.x];
    if (i < N_NODES) {
        offs[i] = excl;
        dinv[i] = rsqrtf((float)(v + 1));
    }
    if (i == N_NODES - 1) offs[N_NODES] = excl + v;
}

// ---------- merged: scatter edges into CSR + canonicalize x (plane-major, *dinv) ----------
__global__ void scatconv_kernel(const int* __restrict__ src, const int* __restrict__ dst,
                                const int* __restrict__ offs, int* __restrict__ cursor,
                                int* __restrict__ srcs, const void* __restrict__ xsrc,
                                u16* __restrict__ xs4, const int* __restrict__ flag,
                                const float* __restrict__ dinv) {
    int b = blockIdx.x;
    if (b < SCAT_BLOCKS) {
        int e = b * 256 + threadIdx.x;
        if (e < N_EDGES) {
            int d = dst[e];
            int p = offs[d] + atomicAdd(&cursor[d], 1);
            srcs[p] = src[e];
        }
    } else {
        int i = (b - SCAT_BLOCKS) * 256 + threadIdx.x;
        if (i < N_NODES * 32) {
            int r = i >> 5, c = i & 31;
            float v = (*flag) ? bf2f(((const u16*)xsrc)[i]) : ((const float*)xsrc)[i];
            xs4[(size_t)(c >> 3) * (N_NODES * 8) + (size_t)r * 8 + (c & 7)] =
                f2bf(v * dinv[r]);
        }
    }
}

// ---------- agg1: XCD-sliced conv1 aggregation in x-space (K=32, 4 planes) ----------
__global__ __launch_bounds__(256, 4) void agg1_kernel(const u16* __restrict__ xs4,
                                                      const int* __restrict__ offs,
                                                      const int* __restrict__ srcs,
                                                      const float* __restrict__ dinv,
                                                      u16* __restrict__ axs) {
    const int p = blockIdx.x & 3;
    const int r = (blockIdx.x >> 2) * 256 + threadIdx.x;
    if (r >= N_NODES) return;
    const u16* base = xs4 + (size_t)p * (N_NODES * 8);
    float acc[8];
    {
        uint4 own = *(const uint4*)(base + (size_t)r * 8);
        u32 w4[4] = {own.x, own.y, own.z, own.w};
#pragma unroll
        for (int t = 0; t < 4; t++) {
            float2 f = bfx2(w4[t]);
            acc[2 * t] = f.x;
            acc[2 * t + 1] = f.y;
        }
    }
    const int e0 = offs[r], e1 = offs[r + 1];
    for (int e = e0; e < e1; e += 4) {
        int ss[4];
        float mm[4];
        ss[0] = srcs[e];
        mm[0] = 1.f;
#pragma unroll
        for (int j = 1; j < 4; j++) {
            ss[j] = srcs[min(e + j, e1 - 1)];
            mm[j] = (e + j < e1) ? 1.f : 0.f;
        }
        uint4 rr[4];
#pragma unroll
        for (int j = 0; j < 4; j++) rr[j] = *(const uint4*)(base + (size_t)ss[j] * 8);
#pragma unroll
        for (int j = 0; j < 4; j++) {
            u32 w4[4] = {rr[j].x, rr[j].y, rr[j].z, rr[j].w};
#pragma unroll
            for (int t = 0; t < 4; t++) {
                float2 f = bfx2(w4[t]);
                acc[2 * t] = fmaf(f.x, mm[j], acc[2 * t]);
                acc[2 * t + 1] = fmaf(f.y, mm[j], acc[2 * t + 1]);
            }
        }
    }
    const float di = dinv[r];
    uint4 outv;
    u32* pk = (u32*)&outv;
#pragma unroll
    for (int t = 0; t < 4; t++)
        pk[t] = (u32)f2bf(acc[2 * t] * di) | ((u32)f2bf(acc[2 * t + 1] * di) << 16);
    *(uint4*)(axs + (size_t)r * 32 + p * 8) = outv;
}

// ---------- agg2: XCD-sliced conv2 aggregation (K=128, 8 planes) ----------
__global__ __launch_bounds__(256, 4) void agg2_kernel(const u16* __restrict__ P2,
                                                      const int* __restrict__ offs,
                                                      const int* __restrict__ srcs,
                                                      const float* __restrict__ dinv,
                                                      const u16* __restrict__ b2,
                                                      u16* __restrict__ x2p) {
    const int p = blockIdx.x & 7;
    const int t = threadIdx.x;
    const int r = (blockIdx.x >> 3) * 128 + (t >> 1);
    const int half = t & 1;
    if (r >= N_NODES) return;
    const u16* base = P2 + (size_t)p * (N_NODES * 16) + half * 8;
    float acc[8];
    {
        uint4 own = *(const uint4*)(base + (size_t)r * 16);
        u32 w4[4] = {own.x, own.y, own.z, own.w};
#pragma unroll
        for (int j = 0; j < 4; j++) {
            float2 f = bfx2(w4[j]);
            acc[2 * j] = f.x;
            acc[2 * j + 1] = f.y;
        }
    }
    const int e0 = offs[r], e1 = offs[r + 1];
    for (int e = e0; e < e1; e += 4) {
        int ss[4];
        float mm[4];
        ss[0] = srcs[e];
        mm[0] = 1.f;
#pragma unroll
        for (int j = 1; j < 4; j++) {
            ss[j] = srcs[min(e + j, e1 - 1)];
            mm[j] = (e + j < e1) ? 1.f : 0.f;
        }
        uint4 rr[4];
#pragma unroll
        for (int j = 0; j < 4; j++) rr[j] = *(const uint4*)(base + (size_t)ss[j] * 16);
#pragma unroll
        for (int j = 0; j < 4; j++) {
            u32 w4[4] = {rr[j].x, rr[j].y, rr[j].z, rr[j].w};
#pragma unroll
            for (int k = 0; k < 4; k++) {
                float2 f = bfx2(w4[k]);
                acc[2 * k] = fmaf(f.x, mm[j], acc[2 * k]);
                acc[2 * k + 1] = fmaf(f.y, mm[j], acc[2 * k + 1]);
            }
        }
    }
    const float di = dinv[r];
    uint4 bb = *(const uint4*)(b2 + p * 16 + half * 8);
    u32 bw[4] = {bb.x, bb.y, bb.z, bb.w};
    uint4 outv;
    u32* pk = (u32*)&outv;
#pragma unroll
    for (int j = 0; j < 4; j++) {
        float2 fb = bfx2(bw[j]);
        float vx = fmaxf(fmaf(acc[2 * j], di, fb.x), 0.f);
        float vy = fmaxf(fmaf(acc[2 * j + 1], di, fb.y), 0.f);
        pk[j] = (u32)f2bf(vx) | ((u32)f2bf(vy) << 16);
    }
    *(uint4*)(x2p + (size_t)p * (N_NODES * 16) + (size_t)r * 16 + half * 8) = outv;
}

// ---------- gemmx: chained W1/W2 GEMMs (round-6 proven: LDS-staged W) ----------
__global__ __launch_bounds__(256, 3) void gemmx_kernel(
    const u16* __restrict__ axs, const u16* __restrict__ W1t, const u16* __restrict__ b1,
    const u16* __restrict__ W2t, u16* __restrict__ P2, const float* __restrict__ dinv, int M) {
    __shared__ __align__(16) u16 ldsA[128 * 40];   // W1t staged; later 4x per-wave [32][40] tbuf
    __shared__ __align__(16) u16 ldsB[128 * 136];  // W2t staged

    const int tid = threadIdx.x;
    const int wave = tid >> 6;
    const int lane = tid & 63;
    const int l15 = lane & 15;
    const int quad = lane >> 4;
    const int row0 = blockIdx.x * 128 + wave * 32;

    {  // stage W1t [128][32] -> ldsA [128][40]
        const u32* g = (const u32*)W1t;
        u32* l = (u32*)ldsA;
        for (int i = tid; i < 128 * 16; i += 256) {
            int n = i >> 4, j = i & 15;
            l[n * 20 + j] = g[i];
        }
    }
    {  // stage W2t [128][128] -> ldsB [128][136] via uint4 (8 iters/thread)
        const uint4* g = (const uint4*)W2t;
        uint4* l = (uint4*)ldsB;  // row stride 17 uint4 (= 272 B)
        for (int i = tid; i < 128 * 16; i += 256) {
            int n = i >> 4, j = i & 15;
            l[n * 17 + j] = g[i];
        }
    }

    uint4 gr1[2];
#pragma unroll
    for (int rt = 0; rt < 2; rt++) {
        int r = min(row0 + rt * 16 + l15, M - 1);
        gr1[rt] = *(const uint4*)(axs + (size_t)r * 32 + quad * 8);
    }
    __syncthreads();

    f32x4 acc1[2][8];
#pragma unroll
    for (int rt = 0; rt < 2; rt++)
#pragma unroll
        for (int nt = 0; nt < 8; nt++) acc1[rt][nt] = {0.f, 0.f, 0.f, 0.f};
#pragma unroll
    for (int nt = 0; nt < 8; nt++) {
        bf16x8 bf = *(const bf16x8*)&ldsA[(nt * 16 + l15) * 40 + quad * 8];
        acc1[0][nt] = __builtin_amdgcn_mfma_f32_16x16x32_bf16(
            __builtin_bit_cast(bf16x8, gr1[0]), bf, acc1[0][nt], 0, 0, 0);
        acc1[1][nt] = __builtin_amdgcn_mfma_f32_16x16x32_bf16(
            __builtin_bit_cast(bf16x8, gr1[1]), bf, acc1[1][nt], 0, 0, 0);
    }
    __syncthreads();  // all waves done with ldsA -> safe to reuse as tbuf

    float bcol[8];
#pragma unroll
    for (int nt = 0; nt < 8; nt++) bcol[nt] = bf2f(b1[nt * 16 + l15]);
    u16* tb = ldsA + wave * 1280;  // per-wave [32][40]
    uint4 gr2[2][4];
#pragma unroll
    for (int kt = 0; kt < 4; kt++) {
#pragma unroll
        for (int rt = 0; rt < 2; rt++)
#pragma unroll
            for (int c2 = 0; c2 < 2; c2++) {
                int nt = 2 * kt + c2;
#pragma unroll
                for (int i = 0; i < 4; i++) {
                    float v = fmaxf(acc1[rt][nt][i] + bcol[nt], 0.f);
                    tb[(rt * 16 + quad * 4 + i) * 40 + c2 * 16 + l15] = f2bf(v);
                }
            }
#pragma unroll
        for (int rt = 0; rt < 2; rt++)
            gr2[rt][kt] = *(const uint4*)&tb[(rt * 16 + l15) * 40 + quad * 8];
    }

    f32x4 acc2[2][8];
#pragma unroll
    for (int rt = 0; rt < 2; rt++)
#pragma unroll
        for (int nt = 0; nt < 8; nt++) acc2[rt][nt] = {0.f, 0.f, 0.f, 0.f};
#pragma unroll
    for (int kt = 0; kt < 4; kt++) {
#pragma unroll
        for (int nt = 0; nt < 8; nt++) {
            bf16x8 bf = *(const bf16x8*)&ldsB[(nt * 16 + l15) * 136 + kt * 32 + quad * 8];
            acc2[0][nt] = __builtin_amdgcn_mfma_f32_16x16x32_bf16(
                __builtin_bit_cast(bf16x8, gr2[0][kt]), bf, acc2[0][nt], 0, 0, 0);
            acc2[1][nt] = __builtin_amdgcn_mfma_f32_16x16x32_bf16(
                __builtin_bit_cast(bf16x8, gr2[1][kt]), bf, acc2[1][nt], 0, 0, 0);
        }
    }

#pragma unroll
    for (int rt = 0; rt < 2; rt++)
#pragma unroll
        for (int i = 0; i < 4; i++) {
            int r = row0 + rt * 16 + quad * 4 + i;
            if (r < M) {
                float ds = dinv[r];
#pragma unroll
                for (int nt = 0; nt < 8; nt++)
                    P2[(size_t)nt * (N_NODES * 16) + (size_t)r * 16 + l15] =
                        f2bf(acc2[rt][nt][i] * ds);
            }
        }
}

// ---------- gemm3: y3 = x2 @ W3 + b3 (+BN stats), SWAPPED MFMA operands (round-10) ----------
// 128-row blocks (verified optimum vs split-N/split-M). Round-12: W staged via uint4
// (8 iters/thread vs 32 scalar) -- same LDS layout (136 u16 = 17 uint4/row).
__global__ __launch_bounds__(256, 3) void gemm3_kernel(
    const u16* __restrict__ A, const u16* __restrict__ Wt, const u16* __restrict__ bias,
    u16* __restrict__ C, float* __restrict__ bn_sum, float* __restrict__ bn_sumsq, int M) {
    constexpr int KP = 136;
    __shared__ __align__(16) u16 Wl[128 * KP];
    __shared__ float csum[128], csumsq[128];

    const int tid = threadIdx.x;
    const int wave = tid >> 6;
    const int lane = tid & 63;
    const int l15 = lane & 15;
    const int quad = lane >> 4;
    const int row0 = blockIdx.x * 128 + wave * 32;

    // prefetch A fragments from plane-major layout: 8 x 16B in flight while W stages
    uint4 ra[2][4];
    int nd[2];
#pragma unroll
    for (int rt = 0; rt < 2; rt++) {
        nd[rt] = row0 + rt * 16 + l15;
        int r = min(nd[rt], M - 1);
#pragma unroll
        for (int kt = 0; kt < 4; kt++) {
            int plane = 2 * kt + (quad >> 1);
            ra[rt][kt] = *(const uint4*)(A + (size_t)plane * (N_NODES * 16) + (size_t)r * 16 +
                                         (quad & 1) * 8);
        }
    }

    {  // stage W3t [128][128] -> Wl [128][136] via uint4 (8 iters/thread)
        const uint4* g = (const uint4*)Wt;
        uint4* l = (uint4*)Wl;  // row stride 17 uint4 (= 272 B, 16B-aligned)
        for (int i = tid; i < 128 * 16; i += 256) {
            int n = i >> 4, j = i & 15;
            l[n * 17 + j] = g[i];
        }
    }
    if (tid < 128) {
        csum[tid] = 0.f;
        csumsq[tid] = 0.f;
    }
    __syncthreads();

    f32x4 acc[2][8];
#pragma unroll
    for (int rt = 0; rt < 2; rt++)
#pragma unroll
        for (int nt = 0; nt < 8; nt++) acc[rt][nt] = {0.f, 0.f, 0.f, 0.f};

#pragma unroll
    for (int kt = 0; kt < 4; kt++) {
        bf16x8 a0 = __builtin_bit_cast(bf16x8, ra[0][kt]);
        bf16x8 a1 = __builtin_bit_cast(bf16x8, ra[1][kt]);
#pragma unroll
        for (int nt = 0; nt < 8; nt++) {
            bf16x8 wf = *(const bf16x8*)&Wl[(nt * 16 + l15) * KP + kt * 32 + quad * 8];
            acc[0][nt] = __builtin_amdgcn_mfma_f32_16x16x32_bf16(wf, a0, acc[0][nt], 0, 0, 0);
            acc[1][nt] = __builtin_amdgcn_mfma_f32_16x16x32_bf16(wf, a1, acc[1][nt], 0, 0, 0);
        }
    }

    // epilogue: per nt -> bias, plane-major uint2 store, stats reduce
    const bool ok0 = nd[0] < M, ok1 = nd[1] < M;
#pragma unroll
    for (int nt = 0; nt < 8; nt++) {
        uint2 braw = *(const uint2*)(bias + nt * 16 + quad * 4);
        float2 f0 = bfx2(braw.x), f1 = bfx2(braw.y);
        float bb[4] = {f0.x, f0.y, f1.x, f1.y};
        float v0[4], v1[4];
#pragma unroll
        for (int i = 0; i < 4; i++) {
            v0[i] = ok0 ? (acc[0][nt][i] + bb[i]) : 0.f;
            v1[i] = ok1 ? (acc[1][nt][i] + bb[i]) : 0.f;
        }
        u16* Cp = C + (size_t)nt * (N_NODES * 16);
        if (ok0) {
            uint2 st;
            st.x = (u32)f2bf(v0[0]) | ((u32)f2bf(v0[1]) << 16);
            st.y = (u32)f2bf(v0[2]) | ((u32)f2bf(v0[3]) << 16);
            *(uint2*)(Cp + (size_t)nd[0] * 16 + quad * 4) = st;
        }
        if (ok1) {
            uint2 st;
            st.x = (u32)f2bf(v1[0]) | ((u32)f2bf(v1[1]) << 16);
            st.y = (u32)f2bf(v1[2]) | ((u32)f2bf(v1[3]) << 16);
            *(uint2*)(Cp + (size_t)nd[1] * 16 + quad * 4) = st;
        }
        // stats: sum over this thread's 2 nodes, then over the 16-lane node group
#pragma unroll
        for (int i = 0; i < 4; i++) {
            float s = v0[i] + v1[i];
            float q = v0[i] * v0[i] + v1[i] * v1[i];
#pragma unroll
            for (int m = 1; m < 16; m <<= 1) {
                s += __shfl_xor(s, m);
                q += __shfl_xor(q, m);
            }
            if (l15 == 0) {
                atomicAdd(&csum[nt * 16 + quad * 4 + i], s);
                atomicAdd(&csumsq[nt * 16 + quad * 4 + i], q);
            }
        }
    }
    __syncthreads();
    if (tid < 128) {
        atomicAdd(&bn_sum[tid], csum[tid]);
        atomicAdd(&bn_sumsq[tid], csumsq[tid]);
    }
}

// ---------- gemm4: relu(relu(BN(y3)) @ W4 + b4) -> segment max (round-10 + uint4 stage) ----------
// bnstats folded in; W4 staged via uint4; A read plane-major; LDS-pre-reduced pooling.
__global__ __launch_bounds__(256, 3) void gemm4_kernel(
    const u16* __restrict__ A, const u16* __restrict__ Wt, const u16* __restrict__ bias,
    const float* __restrict__ bn_sum, const float* __restrict__ bn_sumsq,
    const u16* __restrict__ g1, const u16* __restrict__ be1, const int* __restrict__ batch,
    u32* __restrict__ pooled, int M) {
    constexpr int KP = 136;
    __shared__ __align__(16) u16 Wl[128 * KP];
    __shared__ u32 lmax[4 * 128];
    __shared__ float sscale[128], sshift[128];

    const int tid = threadIdx.x;
    const int wave = tid >> 6;
    const int lane = tid & 63;
    const int l15 = lane & 15;
    const int quad = lane >> 4;
    const int row0 = blockIdx.x * 128 + wave * 32;

    // prefetch raw A fragments (plane-major)
    uint4 ra[2][4];
#pragma unroll
    for (int rt = 0; rt < 2; rt++) {
        int r = min(row0 + rt * 16 + l15, M - 1);
#pragma unroll
        for (int kt = 0; kt < 4; kt++) {
            int plane = 2 * kt + (quad >> 1);
            ra[rt][kt] = *(const uint4*)(A + (size_t)plane * (N_NODES * 16) + (size_t)r * 16 +
                                         (quad & 1) * 8);
        }
    }

    {  // stage W4t via uint4 (8 iters/thread)
        const uint4* g = (const uint4*)Wt;
        uint4* l = (uint4*)Wl;
        for (int i = tid; i < 128 * 16; i += 256) {
            int n = i >> 4, j = i & 15;
            l[n * 17 + j] = g[i];
        }
    }
    for (int i = tid; i < 512; i += 256) lmax[i] = 0u;
    if (tid < 128) {  // inline bnstats: raw sums -> scale/shift
        float mu = bn_sum[tid] / (float)N_NODES;
        float var = bn_sumsq[tid] / (float)N_NODES - mu * mu;
        float rstd = rsqrtf(var + EPS);
        float sc = rstd * bf2f(g1[tid]);
        sscale[tid] = sc;
        sshift[tid] = bf2f(be1[tid]) - mu * sc;
    }

    const int base = blockIdx.x * 128;
    const int gfirst = batch[min(base, M - 1)];
    const int glast = batch[min(base + 127, M - 1)];
    const bool fast = (glast - gfirst) < 4;
    __syncthreads();

    f32x4 acc[2][8];
#pragma unroll
    for (int rt = 0; rt < 2; rt++)
#pragma unroll
        for (int nt = 0; nt < 8; nt++) acc[rt][nt] = {0.f, 0.f, 0.f, 0.f};

#pragma unroll
    for (int kt = 0; kt < 4; kt++) {
        float s8[8], h8[8];
#pragma unroll
        for (int t = 0; t < 8; t++) {
            s8[t] = sscale[kt * 32 + quad * 8 + t];
            h8[t] = sshift[kt * 32 + quad * 8 + t];
        }
        bf16x8 af[2];
#pragma unroll
        for (int rt = 0; rt < 2; rt++) {
            u32 w4[4] = {ra[rt][kt].x, ra[rt][kt].y, ra[rt][kt].z, ra[rt][kt].w};
            bf16x8 tmp;
#pragma unroll
            for (int t = 0; t < 4; t++) {
                float2 f = bfx2(w4[t]);
                f.x = fmaxf(fmaf(f.x, s8[2 * t], h8[2 * t]), 0.f);
                f.y = fmaxf(fmaf(f.y, s8[2 * t + 1], h8[2 * t + 1]), 0.f);
                tmp[2 * t] = (short)f2bf(f.x);
                tmp[2 * t + 1] = (short)f2bf(f.y);
            }
            af[rt] = tmp;
        }
#pragma unroll
        for (int nt = 0; nt < 8; nt++) {
            bf16x8 bf = *(const bf16x8*)&Wl[(nt * 16 + l15) * KP + kt * 32 + quad * 8];
            acc[0][nt] = __builtin_amdgcn_mfma_f32_16x16x32_bf16(af[0], bf, acc[0][nt], 0, 0, 0);
            acc[1][nt] = __builtin_amdgcn_mfma_f32_16x16x32_bf16(af[1], bf, acc[1][nt], 0, 0, 0);
        }
    }

    float b[8];
#pragma unroll
    for (int nt = 0; nt < 8; nt++) b[nt] = bf2f(bias[nt * 16 + l15]);
    float cur[8];
#pragma unroll
    for (int nt = 0; nt < 8; nt++) cur[nt] = 0.f;
    int curg = -1;
#pragma unroll
    for (int rt = 0; rt < 2; rt++)
#pragma unroll
        for (int i = 0; i < 4; i++) {
            int r = row0 + rt * 16 + quad * 4 + i;
            if (r < M) {
                int g = batch[r];
                if (g != curg) {
                    if (curg >= 0) {
#pragma unroll
                        for (int nt = 0; nt < 8; nt++)
                            if (cur[nt] > 0.f) {
                                u32 bits = __float_as_uint(cur[nt]);
                                if (fast)
                                    atomicMax(&lmax[(curg - gfirst) * 128 + nt * 16 + l15], bits);
                                else
                                    atomicMax(&pooled[curg * 128 + nt * 16 + l15], bits);
                            }
                    }
                    curg = g;
#pragma unroll
                    for (int nt = 0; nt < 8; nt++) cur[nt] = 0.f;
                }
#pragma unroll
                for (int nt = 0; nt < 8; nt++)
                    cur[nt] = fmaxf(cur[nt], fmaxf(acc[rt][nt][i] + b[nt], 0.f));
            }
        }
    if (curg >= 0) {
#pragma unroll
        for (int nt = 0; nt < 8; nt++)
            if (cur[nt] > 0.f) {
                u32 bits = __float_as_uint(cur[nt]);
                if (fast)
                    atomicMax(&lmax[(curg - gfirst) * 128 + nt * 16 + l15], bits);
                else
                    atomicMax(&pooled[curg * 128 + nt * 16 + l15], bits);
            }
    }
    __syncthreads();
    if (fast) {
        int ngr = glast - gfirst + 1;
        for (int i = tid; i < ngr * 128; i += 256) {
            u32 v = lmax[i];
            if (v) atomicMax(&pooled[gfirst * 128 + i], v);
        }
    }
}

// ---------- head part 1: zf[64,64] = pooled[64,128] @ W5 + b5 ----------
__global__ __launch_bounds__(256) void head1_kernel(const u32* __restrict__ pooled,
                                                    const u16* __restrict__ W5,
                                                    const u16* __restrict__ b5,
                                                    float* __restrict__ zf) {
    __shared__ float red[4][64];
    int g = blockIdx.x;
    int c = threadIdx.x & 63;
    int kq = threadIdx.x >> 6;
    const u32* prow = pooled + g * 128;
    float p = 0.f;
    for (int k = kq * 32; k < kq * 32 + 32; k++)
        p = fmaf(__uint_as_float(prow[k]), bf2f(W5[k * 64 + c]), p);
    red[kq][c] = p;
    __syncthreads();
    if (kq == 0) zf[g * 64 + c] = red[0][c] + red[1][c] + red[2][c] + red[3][c] + bf2f(b5[c]);
}

// ---------- head part 2 ----------
__global__ __launch_bounds__(64) void head2_kernel(const float* __restrict__ zf,
                                                   const u16* __restrict__ g2,
                                                   const u16* __restrict__ be2,
                                                   const u16* __restrict__ W6,
                                                   const u16* __restrict__ b6,
                                                   void* __restrict__ outv,
                                                   const int* __restrict__ flag) {
    __shared__ float Z[64][65];
    __shared__ float sc[64], sh[64], w6[64];
    int t = threadIdx.x;
    for (int idx = t; idx < 4096; idx += 64) Z[idx >> 6][idx & 63] = zf[idx];
    w6[t] = bf2f(W6[t]);
    __syncthreads();
    {
        float s = 0.f, sq = 0.f;
        for (int g = 0; g < 64; g++) {
            float v = Z[g][t];
            s += v;
            sq += v * v;
        }
        float mu = s * (1.f / 64.f);
        float var = sq * (1.f / 64.f) - mu * mu;
        float rstd = rsqrtf(var + EPS);
        float scale = rstd * bf2f(g2[t]);
        sc[t] = scale;
        sh[t] = bf2f(be2[t]) - mu * scale;
    }
    __syncthreads();
    float o = 0.f;
    for (int c = 0; c < 64; c++)
        o = fmaf(fmaxf(fmaf(Z[t][c], sc[c], sh[c]), 0.f), w6[c], o);
    float res = o + bf2f(b6[0]);
    if (*flag)
        ((u16*)outv)[t] = f2bf(res);
    else
        ((float*)outv)[t] = res;
}

extern "C" void kernel_launch(void* const* d_in, const int* in_sizes, int n_in, void* d_out,
                              int out_size, void* d_ws, size_t ws_size, hipStream_t stream) {
    const void* x = d_in[0];
    const int* ei = (const int*)d_in[1];
    const int* bat = (const int*)d_in[2];

    char* ws = (char*)d_ws;
    int* counts = (int*)(ws + WS_COUNTS);
    int* cursor = (int*)(ws + WS_CURSOR);
    u32* pooled = (u32*)(ws + WS_POOLED);
    float* bnsum = (float*)(ws + WS_BNSUM);
    float* bnssq = (float*)(ws + WS_BNSUMSQ);
    int* flag = (int*)(ws + WS_FLAG);
    int* offs = (int*)(ws + WS_OFFSETS);
    float* dinv = (float*)(ws + WS_DINV);
    int* partials = (int*)(ws + WS_DINV2);
    int* srcs = (int*)(ws + WS_SRCS);
    float* zf = (float*)(ws + WS_ZF);
    u16* cw = (u16*)(ws + WS_CANONW);
    u16* P2 = (u16*)(ws + WS_BUFA);             // plane-major hs2 [8][N][16]
    u16* xs4 = (u16*)(ws + WS_BUFB);            // plane-major xs [4][N][8] (dead after agg1)
    u16* axs = (u16*)(ws + WS_BUFB) + 3200000;  // [N][32] at BUFB+6.4MB (dead after gemmx)
    u16* x2p = (u16*)(ws + WS_BUFB);            // plane-major x2/y3 [8][N][16], in-place reuse

    const int* esrc = ei;
    const int* edst = ei + N_EDGES;

    hipMemsetAsync(ws, 0, ZERO_BYTES, stream);
    detect_kernel<<<1, 256, 0, stream>>>((const u32*)x, flag);

    SmallArgs sa;
    const int cw_off[16] = {CW_W1, CW_B1, CW_W2, CW_B2, CW_W3, CW_B3, CW_G1, CW_BE1,
                            CW_W4, CW_B4, CW_W5, CW_B5, CW_G2, CW_BE2, CW_W6, CW_B6};
    const int cw_n[16] = {4096, 128, 16384, 128, 16384, 128, 128, 128,
                          16384, 128, 8192, 64, 64, 64, 64, 1};
    const int cw_c[16] = {128, 0, 128, 0, 128, 0, 0, 0, 128, 0, 0, 0, 0, 0, 0, 0};
    for (int j = 0; j < 16; j++) {
        sa.src[j] = d_in[3 + j];
        sa.n[j] = cw_n[j];
        sa.off[j] = cw_off[j];
        sa.cols[j] = cw_c[j];
    }
    convs_kernel<<<64, 256, 0, stream>>>(sa, cw, flag);

    deg_kernel<<<(N_EDGES + 255) / 256, 256, 0, stream>>>(edst, counts);
    reduce_kernel<<<SCAN_BLOCKS, 256, 0, stream>>>(counts, partials);
    scanpart_kernel<<<1, 512, 0, stream>>>(partials);
    offsets_kernel<<<SCAN_BLOCKS, 256, 0, stream>>>(counts, partials, offs, dinv);
    // merged scatter + convx (both depend only on offsets)
    scatconv_kernel<<<SCAT_BLOCKS + (N_NODES * 32 + 255) / 256, 256, 0, stream>>>(
        esrc, edst, offs, cursor, srcs, x, xs4, flag, dinv);

    const int gb = (N_NODES + 127) / 128;
    // agg1: axs = aggnorm(xs) (XCD-sliced gather, K=32)
    agg1_kernel<<<4 * SCAN_BLOCKS, 256, 0, stream>>>(xs4, offs, srcs, dinv, axs);
    // gemmx: x1 = relu(axs@W1 + b1); hs2 = (x1@W2)*dinv -> P2 plane-major
    gemmx_kernel<<<gb, 256, 0, stream>>>(axs, cw + CW_W1, cw + CW_B1, cw + CW_W2, P2, dinv,
                                         N_NODES);
    // agg2: x2 = relu((agg hs2 + hs2)*dinv + b2) (XCD-sliced gather) -> x2p plane-major
    agg2_kernel<<<8 * gb, 256, 0, stream>>>(P2, offs, srcs, dinv, cw + CW_B2, x2p);
    // gemm3: y3 = x2 @ W3 + b3 (+BN stats) -> in place over x2p (block-local alias, safe)
    gemm3_kernel<<<gb, 256, 0, stream>>>(x2p, cw + CW_W3, cw + CW_B3, x2p, bnsum, bnssq,
                                         N_NODES);
    // gemm4 (bnstats folded in): relu(relu(BN(y3)) @ W4 + b4) -> segment max into pooled
    gemm4_kernel<<<gb, 256, 0, stream>>>(x2p, cw + CW_W4, cw + CW_B4, bnsum, bnssq, cw + CW_G1,
                                         cw + CW_BE1, bat, pooled, N_NODES);
    // head
    head1_kernel<<<N_GRAPHS, 256, 0, stream>>>(pooled, cw + CW_W5, cw + CW_B5, zf);
    head2_kernel<<<1, 64, 0, stream>>>(zf, cw + CW_G2, cw + CW_BE2, cw + CW_W6, cw + CW_B6,
                                       d_out, flag);
}

// Round 13
// 304.859 us; speedup vs baseline: 1.0862x; 1.0281x over previous
//
#include <hip/hip_runtime.h>

#define N_NODES 100000
#define N_EDGES 600000
#define N_GRAPHS 64
#define EPS 1e-5f
#define SCAN_BLOCKS 391   // ceil(N_NODES/256)
#define SCAT_BLOCKS 2344  // ceil(N_EDGES/256)

typedef unsigned short u16;
typedef unsigned int u32;
typedef __attribute__((ext_vector_type(8))) short bf16x8;
typedef __attribute__((ext_vector_type(4))) float f32x4;

// ---------- bf16 helpers ----------
__device__ __forceinline__ float bf2f(u16 u) { return __uint_as_float(((u32)u) << 16); }
__device__ __forceinline__ u16 f2bf(float f) {
    u32 u = __float_as_uint(f);
    u += 0x7FFFu + ((u >> 16) & 1u);
    return (u16)(u >> 16);
}
__device__ __forceinline__ float2 bfx2(u32 v) {
    float2 r;
    r.x = __uint_as_float(v << 16);
    r.y = __uint_as_float(v & 0xFFFF0000u);
    return r;
}

// ---------- workspace layout (bytes, 512-aligned) ----------
// zeroed region first
#define WS_COUNTS   ((size_t)0)          // int[N]
#define WS_CURSOR   ((size_t)400384)     // int[N]
#define WS_POOLED   ((size_t)800768)     // u32[64*128] (float bits, >=0)
#define WS_BNSUM    ((size_t)833536)     // float[128]
#define WS_BNSUMSQ  ((size_t)834048)     // float[128]
#define WS_FLAG     ((size_t)834560)     // int (1 = inputs are bf16, 0 = f32)
#define ZERO_BYTES  ((size_t)835072)
// non-zeroed
#define WS_OFFSETS  ((size_t)835072)     // int[N+1]
#define WS_DINV     ((size_t)1235456)    // float[N]
#define WS_DINV2    ((size_t)1635840)    // float[N]; start doubles as scan partials (dead by then)
#define WS_SRCS     ((size_t)2036224)    // int[E]
#define WS_ZF       ((size_t)4436736)    // float[64*64]
#define WS_CANONW   ((size_t)4453120)    // u16[62465] canonical weights (W1-W4 TRANSPOSED)
#define WS_BUFA     ((size_t)4578560)    // 25.6 MB: P2 plane-major [8][N][16] bf16
#define WS_BUFB     ((size_t)30178560)   // 25.6 MB: xs4[4][N][8] -> axs[N][32] (at +6.4MB) -> x2/y3 plane-major [8][N][16]
// total ~53.2 MB (unchanged)

// canonical weight offsets (u16 units); W1..W4 stored transposed [n][k]
#define CW_W1 0
#define CW_B1 4096
#define CW_W2 4224
#define CW_B2 20608
#define CW_W3 20736
#define CW_B3 37120
#define CW_G1 37248
#define CW_BE1 37376
#define CW_W4 37504
#define CW_B4 53888
#define CW_W5 54016
#define CW_B5 62208
#define CW_G2 62272
#define CW_BE2 62336
#define CW_W6 62400
#define CW_B6 62464

// ---------- dtype detector ----------
__global__ void detect_kernel(const u32* __restrict__ xraw, int* __restrict__ flag) {
    __shared__ int cnt;
    if (threadIdx.x == 0) cnt = 0;
    __syncthreads();
    int c = 0;
    for (int i = threadIdx.x; i < 2048; i += 256) {
        u32 w = xraw[i];
        float a = fabsf(__uint_as_float((w & 0xFFFFu) << 16));
        if (a == 0.f || (a > 1e-8f && a < 1e4f)) c++;
    }
    atomicAdd(&cnt, c);
    __syncthreads();
    if (threadIdx.x == 0) *flag = (cnt > 1024) ? 1 : 0;
}

// ---------- canonicalize 16 weight arrays to bf16 (optionally transposed) ----------
struct SmallArgs {
    const void* src[16];
    int n[16];
    int off[16];
    int cols[16];
};
__global__ void convs_kernel(SmallArgs a, u16* __restrict__ dst, const int* __restrict__ flag) {
    int i = blockIdx.x * 256 + threadIdx.x;
    int isbf = *flag;
#pragma unroll
    for (int j = 0; j < 16; j++)
        if (i < a.n[j]) {
            u16 v = isbf ? ((const u16*)a.src[j])[i] : f2bf(((const float*)a.src[j])[i]);
            if (a.cols[j] > 0) {
                int k = i / a.cols[j];
                int n = i - k * a.cols[j];
                int Kd = a.n[j] / a.cols[j];
                dst[a.off[j] + n * Kd + k] = v;
            } else {
                dst[a.off[j] + i] = v;
            }
        }
}

// ---------- degree histogram ----------
__global__ void deg_kernel(const int* __restrict__ dst, int* __restrict__ counts) {
    int e = blockIdx.x * 256 + threadIdx.x;
    if (e < N_EDGES) atomicAdd(&counts[dst[e]], 1);
}

// ---------- hierarchical scan: phase 1 ----------
__global__ __launch_bounds__(256) void reduce_kernel(const int* __restrict__ counts,
                                                     int* __restrict__ partials) {
    int i = blockIdx.x * 256 + threadIdx.x;
    int v = (i < N_NODES) ? counts[i] : 0;
    for (int off = 32; off > 0; off >>= 1) v += __shfl_down(v, off, 64);
    __shared__ int wsum[4];
    if ((threadIdx.x & 63) == 0) wsum[threadIdx.x >> 6] = v;
    __syncthreads();
    if (threadIdx.x == 0) partials[blockIdx.x] = wsum[0] + wsum[1] + wsum[2] + wsum[3];
}

// ---------- phase 2 ----------
__global__ __launch_bounds__(512) void scanpart_kernel(int* __restrict__ partials) {
    __shared__ int sc[512];
    int t = threadIdx.x;
    int v = (t < SCAN_BLOCKS) ? partials[t] : 0;
    sc[t] = v;
    __syncthreads();
    for (int off = 1; off < 512; off <<= 1) {
        int u = (t >= off) ? sc[t - off] : 0;
        __syncthreads();
        sc[t] += u;
        __syncthreads();
    }
    if (t < SCAN_BLOCKS) partials[t] = sc[t] - v;
}

// ---------- phase 3: offsets + dinv ----------
__global__ __launch_bounds__(256) void offsets_kernel(const int* __restrict__ counts,
                                                      const int* __restrict__ partials,
                                                      int* __restrict__ offs,
                                                      float* __restrict__ dinv) {
    int i = blockIdx.x * 256 + threadIdx.x;
    int lane = threadIdx.x & 63, wv = threadIdx.x >> 6;
    int v = (i < N_NODES) ? counts[i] : 0;
    int sv = v;
    for (int off = 1; off < 64; off <<= 1) {
        int u = __shfl_up(sv, off, 64);
        if (lane >= off) sv += u;
    }
    __shared__ int wsum[4];
    if (lane == 63) wsum[wv] = sv;
    __syncthreads();
    int wpre = 0;
    for (int w = 0; w < wv; w++) wpre += wsum[w];
    int excl = sv - v + wpre + partials[blockIdx.x];
    if (i < N_NODES) {
        offs[i] = excl;
        dinv[i] = rsqrtf((float)(v + 1));
    }
    if (i == N_NODES - 1) offs[N_NODES] = excl + v;
}

// ---------- merged: scatter edges into CSR + canonicalize x (plane-major, *dinv) ----------
__global__ void scatconv_kernel(const int* __restrict__ src, const int* __restrict__ dst,
                                const int* __restrict__ offs, int* __restrict__ cursor,
                                int* __restrict__ srcs, const void* __restrict__ xsrc,
                                u16* __restrict__ xs4, const int* __restrict__ flag,
                                const float* __restrict__ dinv) {
    int b = blockIdx.x;
    if (b < SCAT_BLOCKS) {
        int e = b * 256 + threadIdx.x;
        if (e < N_EDGES) {
            int d = dst[e];
            int p = offs[d] + atomicAdd(&cursor[d], 1);
            srcs[p] = src[e];
        }
    } else {
        int i = (b - SCAT_BLOCKS) * 256 + threadIdx.x;
        if (i < N_NODES * 32) {
            int r = i >> 5, c = i & 31;
            float v = (*flag) ? bf2f(((const u16*)xsrc)[i]) : ((const float*)xsrc)[i];
            xs4[(size_t)(c >> 3) * (N_NODES * 8) + (size_t)r * 8 + (c & 7)] =
                f2bf(v * dinv[r]);
        }
    }
}

// ---------- agg1: XCD-sliced conv1 aggregation in x-space (K=32, 4 planes) ----------
__global__ __launch_bounds__(256, 4) void agg1_kernel(const u16* __restrict__ xs4,
                                                      const int* __restrict__ offs,
                                                      const int* __restrict__ srcs,
                                                      const float* __restrict__ dinv,
                                                      u16* __restrict__ axs) {
    const int p = blockIdx.x & 3;
    const int r = (blockIdx.x >> 2) * 256 + threadIdx.x;
    if (r >= N_NODES) return;
    const u16* base = xs4 + (size_t)p * (N_NODES * 8);
    float acc[8];
    {
        uint4 own = *(const uint4*)(base + (size_t)r * 8);
        u32 w4[4] = {own.x, own.y, own.z, own.w};
#pragma unroll
        for (int t = 0; t < 4; t++) {
            float2 f = bfx2(w4[t]);
            acc[2 * t] = f.x;
            acc[2 * t + 1] = f.y;
        }
    }
    const int e0 = offs[r], e1 = offs[r + 1];
    for (int e = e0; e < e1; e += 4) {
        int ss[4];
        float mm[4];
        ss[0] = srcs[e];
        mm[0] = 1.f;
#pragma unroll
        for (int j = 1; j < 4; j++) {
            ss[j] = srcs[min(e + j, e1 - 1)];
            mm[j] = (e + j < e1) ? 1.f : 0.f;
        }
        uint4 rr[4];
#pragma unroll
        for (int j = 0; j < 4; j++) rr[j] = *(const uint4*)(base + (size_t)ss[j] * 8);
#pragma unroll
        for (int j = 0; j < 4; j++) {
            u32 w4[4] = {rr[j].x, rr[j].y, rr[j].z, rr[j].w};
#pragma unroll
            for (int t = 0; t < 4; t++) {
                float2 f = bfx2(w4[t]);
                acc[2 * t] = fmaf(f.x, mm[j], acc[2 * t]);
                acc[2 * t + 1] = fmaf(f.y, mm[j], acc[2 * t + 1]);
            }
        }
    }
    const float di = dinv[r];
    uint4 outv;
    u32* pk = (u32*)&outv;
#pragma unroll
    for (int t = 0; t < 4; t++)
        pk[t] = (u32)f2bf(acc[2 * t] * di) | ((u32)f2bf(acc[2 * t + 1] * di) << 16);
    *(uint4*)(axs + (size_t)r * 32 + p * 8) = outv;
}

// ---------- agg2: XCD-sliced conv2 aggregation (K=128, 8 planes) ----------
__global__ __launch_bounds__(256, 4) void agg2_kernel(const u16* __restrict__ P2,
                                                      const int* __restrict__ offs,
                                                      const int* __restrict__ srcs,
                                                      const float* __restrict__ dinv,
                                                      const u16* __restrict__ b2,
                                                      u16* __restrict__ x2p) {
    const int p = blockIdx.x & 7;
    const int t = threadIdx.x;
    const int r = (blockIdx.x >> 3) * 128 + (t >> 1);
    const int half = t & 1;
    if (r >= N_NODES) return;
    const u16* base = P2 + (size_t)p * (N_NODES * 16) + half * 8;
    float acc[8];
    {
        uint4 own = *(const uint4*)(base + (size_t)r * 16);
        u32 w4[4] = {own.x, own.y, own.z, own.w};
#pragma unroll
        for (int j = 0; j < 4; j++) {
            float2 f = bfx2(w4[j]);
            acc[2 * j] = f.x;
            acc[2 * j + 1] = f.y;
        }
    }
    const int e0 = offs[r], e1 = offs[r + 1];
    for (int e = e0; e < e1; e += 4) {
        int ss[4];
        float mm[4];
        ss[0] = srcs[e];
        mm[0] = 1.f;
#pragma unroll
        for (int j = 1; j < 4; j++) {
            ss[j] = srcs[min(e + j, e1 - 1)];
            mm[j] = (e + j < e1) ? 1.f : 0.f;
        }
        uint4 rr[4];
#pragma unroll
        for (int j = 0; j < 4; j++) rr[j] = *(const uint4*)(base + (size_t)ss[j] * 16);
#pragma unroll
        for (int j = 0; j < 4; j++) {
            u32 w4[4] = {rr[j].x, rr[j].y, rr[j].z, rr[j].w};
#pragma unroll
            for (int k = 0; k < 4; k++) {
                float2 f = bfx2(w4[k]);
                acc[2 * k] = fmaf(f.x, mm[j], acc[2 * k]);
                acc[2 * k + 1] = fmaf(f.y, mm[j], acc[2 * k + 1]);
            }
        }
    }
    const float di = dinv[r];
    uint4 bb = *(const uint4*)(b2 + p * 16 + half * 8);
    u32 bw[4] = {bb.x, bb.y, bb.z, bb.w};
    uint4 outv;
    u32* pk = (u32*)&outv;
#pragma unroll
    for (int j = 0; j < 4; j++) {
        float2 fb = bfx2(bw[j]);
        float vx = fmaxf(fmaf(acc[2 * j], di, fb.x), 0.f);
        float vy = fmaxf(fmaf(acc[2 * j + 1], di, fb.y), 0.f);
        pk[j] = (u32)f2bf(vx) | ((u32)f2bf(vy) << 16);
    }
    *(uint4*)(x2p + (size_t)p * (N_NODES * 16) + (size_t)r * 16 + half * 8) = outv;
}

// ---------- gemmx: chained W1/W2 GEMMs (round-6 proven: LDS-staged W) ----------
__global__ __launch_bounds__(256, 3) void gemmx_kernel(
    const u16* __restrict__ axs, const u16* __restrict__ W1t, const u16* __restrict__ b1,
    const u16* __restrict__ W2t, u16* __restrict__ P2, const float* __restrict__ dinv, int M) {
    __shared__ __align__(16) u16 ldsA[128 * 40];   // W1t staged; later 4x per-wave [32][40] tbuf
    __shared__ __align__(16) u16 ldsB[128 * 136];  // W2t staged

    const int tid = threadIdx.x;
    const int wave = tid >> 6;
    const int lane = tid & 63;
    const int l15 = lane & 15;
    const int quad = lane >> 4;
    const int row0 = blockIdx.x * 128 + wave * 32;

    {  // stage W1t [128][32] -> ldsA [128][40]
        const u32* g = (const u32*)W1t;
        u32* l = (u32*)ldsA;
        for (int i = tid; i < 128 * 16; i += 256) {
            int n = i >> 4, j = i & 15;
            l[n * 20 + j] = g[i];
        }
    }
    {  // stage W2t [128][128] -> ldsB [128][136]
        const u32* g = (const u32*)W2t;
        u32* l = (u32*)ldsB;
        for (int i = tid; i < 128 * 64; i += 256) {
            int n = i >> 6, j = i & 63;
            l[n * 68 + j] = g[i];
        }
    }

    uint4 gr1[2];
#pragma unroll
    for (int rt = 0; rt < 2; rt++) {
        int r = min(row0 + rt * 16 + l15, M - 1);
        gr1[rt] = *(const uint4*)(axs + (size_t)r * 32 + quad * 8);
    }
    __syncthreads();

    f32x4 acc1[2][8];
#pragma unroll
    for (int rt = 0; rt < 2; rt++)
#pragma unroll
        for (int nt = 0; nt < 8; nt++) acc1[rt][nt] = {0.f, 0.f, 0.f, 0.f};
#pragma unroll
    for (int nt = 0; nt < 8; nt++) {
        bf16x8 bf = *(const bf16x8*)&ldsA[(nt * 16 + l15) * 40 + quad * 8];
        acc1[0][nt] = __builtin_amdgcn_mfma_f32_16x16x32_bf16(
            __builtin_bit_cast(bf16x8, gr1[0]), bf, acc1[0][nt], 0, 0, 0);
        acc1[1][nt] = __builtin_amdgcn_mfma_f32_16x16x32_bf16(
            __builtin_bit_cast(bf16x8, gr1[1]), bf, acc1[1][nt], 0, 0, 0);
    }
    __syncthreads();  // all waves done with ldsA -> safe to reuse as tbuf

    float bcol[8];
#pragma unroll
    for (int nt = 0; nt < 8; nt++) bcol[nt] = bf2f(b1[nt * 16 + l15]);
    u16* tb = ldsA + wave * 1280;  // per-wave [32][40]
    uint4 gr2[2][4];
#pragma unroll
    for (int kt = 0; kt < 4; kt++) {
#pragma unroll
        for (int rt = 0; rt < 2; rt++)
#pragma unroll
            for (int c2 = 0; c2 < 2; c2++) {
                int nt = 2 * kt + c2;
#pragma unroll
                for (int i = 0; i < 4; i++) {
                    float v = fmaxf(acc1[rt][nt][i] + bcol[nt], 0.f);
                    tb[(rt * 16 + quad * 4 + i) * 40 + c2 * 16 + l15] = f2bf(v);
                }
            }
#pragma unroll
        for (int rt = 0; rt < 2; rt++)
            gr2[rt][kt] = *(const uint4*)&tb[(rt * 16 + l15) * 40 + quad * 8];
    }

    f32x4 acc2[2][8];
#pragma unroll
    for (int rt = 0; rt < 2; rt++)
#pragma unroll
        for (int nt = 0; nt < 8; nt++) acc2[rt][nt] = {0.f, 0.f, 0.f, 0.f};
#pragma unroll
    for (int kt = 0; kt < 4; kt++) {
#pragma unroll
        for (int nt = 0; nt < 8; nt++) {
            bf16x8 bf = *(const bf16x8*)&ldsB[(nt * 16 + l15) * 136 + kt * 32 + quad * 8];
            acc2[0][nt] = __builtin_amdgcn_mfma_f32_16x16x32_bf16(
                __builtin_bit_cast(bf16x8, gr2[0][kt]), bf, acc2[0][nt], 0, 0, 0);
            acc2[1][nt] = __builtin_amdgcn_mfma_f32_16x16x32_bf16(
                __builtin_bit_cast(bf16x8, gr2[1][kt]), bf, acc2[1][nt], 0, 0, 0);
        }
    }

#pragma unroll
    for (int rt = 0; rt < 2; rt++)
#pragma unroll
        for (int i = 0; i < 4; i++) {
            int r = row0 + rt * 16 + quad * 4 + i;
            if (r < M) {
                float ds = dinv[r];
#pragma unroll
                for (int nt = 0; nt < 8; nt++)
                    P2[(size_t)nt * (N_NODES * 16) + (size_t)r * 16 + l15] =
                        f2bf(acc2[rt][nt][i] * ds);
            }
        }
}

// ---------- gemm3: y3 = x2 @ W3 + b3 (+BN stats), SWAPPED MFMA operands (round-10) ----------
// 128-row blocks (verified optimum vs split-N/split-M/no-LDS). A read PLANE-MAJOR
// [8][N][16]; C written plane-major in place over x2p (block-local alias).
__global__ __launch_bounds__(256, 3) void gemm3_kernel(
    const u16* __restrict__ A, const u16* __restrict__ Wt, const u16* __restrict__ bias,
    u16* __restrict__ C, float* __restrict__ bn_sum, float* __restrict__ bn_sumsq, int M) {
    constexpr int KP = 136;
    __shared__ __align__(16) u16 Wl[128 * KP];
    __shared__ float csum[128], csumsq[128];

    const int tid = threadIdx.x;
    const int wave = tid >> 6;
    const int lane = tid & 63;
    const int l15 = lane & 15;
    const int quad = lane >> 4;
    const int row0 = blockIdx.x * 128 + wave * 32;

    // prefetch A fragments from plane-major layout: 8 x 16B in flight while W stages
    uint4 ra[2][4];
    int nd[2];
#pragma unroll
    for (int rt = 0; rt < 2; rt++) {
        nd[rt] = row0 + rt * 16 + l15;
        int r = min(nd[rt], M - 1);
#pragma unroll
        for (int kt = 0; kt < 4; kt++) {
            int plane = 2 * kt + (quad >> 1);
            ra[rt][kt] = *(const uint4*)(A + (size_t)plane * (N_NODES * 16) + (size_t)r * 16 +
                                         (quad & 1) * 8);
        }
    }

    {  // stage W3t [128][128] -> Wl [128][136]
        const u32* g = (const u32*)Wt;
        u32* l = (u32*)Wl;
        for (int i = tid; i < 128 * 64; i += 256) {
            int n = i >> 6, j = i & 63;
            l[n * 68 + j] = g[i];
        }
    }
    if (tid < 128) {
        csum[tid] = 0.f;
        csumsq[tid] = 0.f;
    }
    __syncthreads();

    f32x4 acc[2][8];
#pragma unroll
    for (int rt = 0; rt < 2; rt++)
#pragma unroll
        for (int nt = 0; nt < 8; nt++) acc[rt][nt] = {0.f, 0.f, 0.f, 0.f};

#pragma unroll
    for (int kt = 0; kt < 4; kt++) {
        bf16x8 a0 = __builtin_bit_cast(bf16x8, ra[0][kt]);
        bf16x8 a1 = __builtin_bit_cast(bf16x8, ra[1][kt]);
#pragma unroll
        for (int nt = 0; nt < 8; nt++) {
            bf16x8 wf = *(const bf16x8*)&Wl[(nt * 16 + l15) * KP + kt * 32 + quad * 8];
            acc[0][nt] = __builtin_amdgcn_mfma_f32_16x16x32_bf16(wf, a0, acc[0][nt], 0, 0, 0);
            acc[1][nt] = __builtin_amdgcn_mfma_f32_16x16x32_bf16(wf, a1, acc[1][nt], 0, 0, 0);
        }
    }

    // epilogue: per nt -> bias, plane-major uint2 store, stats reduce
    const bool ok0 = nd[0] < M, ok1 = nd[1] < M;
#pragma unroll
    for (int nt = 0; nt < 8; nt++) {
        uint2 braw = *(const uint2*)(bias + nt * 16 + quad * 4);
        float2 f0 = bfx2(braw.x), f1 = bfx2(braw.y);
        float bb[4] = {f0.x, f0.y, f1.x, f1.y};
        float v0[4], v1[4];
#pragma unroll
        for (int i = 0; i < 4; i++) {
            v0[i] = ok0 ? (acc[0][nt][i] + bb[i]) : 0.f;
            v1[i] = ok1 ? (acc[1][nt][i] + bb[i]) : 0.f;
        }
        u16* Cp = C + (size_t)nt * (N_NODES * 16);
        if (ok0) {
            uint2 st;
            st.x = (u32)f2bf(v0[0]) | ((u32)f2bf(v0[1]) << 16);
            st.y = (u32)f2bf(v0[2]) | ((u32)f2bf(v0[3]) << 16);
            *(uint2*)(Cp + (size_t)nd[0] * 16 + quad * 4) = st;
        }
        if (ok1) {
            uint2 st;
            st.x = (u32)f2bf(v1[0]) | ((u32)f2bf(v1[1]) << 16);
            st.y = (u32)f2bf(v1[2]) | ((u32)f2bf(v1[3]) << 16);
            *(uint2*)(Cp + (size_t)nd[1] * 16 + quad * 4) = st;
        }
        // stats: sum over this thread's 2 nodes, then over the 16-lane node group
#pragma unroll
        for (int i = 0; i < 4; i++) {
            float s = v0[i] + v1[i];
            float q = v0[i] * v0[i] + v1[i] * v1[i];
#pragma unroll
            for (int m = 1; m < 16; m <<= 1) {
                s += __shfl_xor(s, m);
                q += __shfl_xor(q, m);
            }
            if (l15 == 0) {
                atomicAdd(&csum[nt * 16 + quad * 4 + i], s);
                atomicAdd(&csumsq[nt * 16 + quad * 4 + i], q);
            }
        }
    }
    __syncthreads();
    if (tid < 128) {
        atomicAdd(&bn_sum[tid], csum[tid]);
        atomicAdd(&bn_sumsq[tid], csumsq[tid]);
    }
}

// ---------- gemm4: relu(relu(BN(y3)) @ W4 + b4) -> segment max (round-10 + inline BN) ----------
// bnstats folded in; A read plane-major; W4 LDS-staged; LDS-pre-reduced pooling.
__global__ __launch_bounds__(256, 3) void gemm4_kernel(
    const u16* __restrict__ A, const u16* __restrict__ Wt, const u16* __restrict__ bias,
    const float* __restrict__ bn_sum, const float* __restrict__ bn_sumsq,
    const u16* __restrict__ g1, const u16* __restrict__ be1, const int* __restrict__ batch,
    u32* __restrict__ pooled, int M) {
    constexpr int KP = 136;
    __shared__ __align__(16) u16 Wl[128 * KP];
    __shared__ u32 lmax[4 * 128];
    __shared__ float sscale[128], sshift[128];

    const int tid = threadIdx.x;
    const int wave = tid >> 6;
    const int lane = tid & 63;
    const int l15 = lane & 15;
    const int quad = lane >> 4;
    const int row0 = blockIdx.x * 128 + wave * 32;

    // prefetch raw A fragments (plane-major)
    uint4 ra[2][4];
#pragma unroll
    for (int rt = 0; rt < 2; rt++) {
        int r = min(row0 + rt * 16 + l15, M - 1);
#pragma unroll
        for (int kt = 0; kt < 4; kt++) {
            int plane = 2 * kt + (quad >> 1);
            ra[rt][kt] = *(const uint4*)(A + (size_t)plane * (N_NODES * 16) + (size_t)r * 16 +
                                         (quad & 1) * 8);
        }
    }

    {  // stage W4t
        const u32* g = (const u32*)Wt;
        u32* l = (u32*)Wl;
        for (int i = tid; i < 128 * 64; i += 256) {
            int n = i >> 6, j = i & 63;
            l[n * 68 + j] = g[i];
        }
    }
    for (int i = tid; i < 512; i += 256) lmax[i] = 0u;
    if (tid < 128) {  // inline bnstats: raw sums -> scale/shift
        float mu = bn_sum[tid] / (float)N_NODES;
        float var = bn_sumsq[tid] / (float)N_NODES - mu * mu;
        float rstd = rsqrtf(var + EPS);
        float sc = rstd * bf2f(g1[tid]);
        sscale[tid] = sc;
        sshift[tid] = bf2f(be1[tid]) - mu * sc;
    }

    const int base = blockIdx.x * 128;
    const int gfirst = batch[min(base, M - 1)];
    const int glast = batch[min(base + 127, M - 1)];
    const bool fast = (glast - gfirst) < 4;
    __syncthreads();

    f32x4 acc[2][8];
#pragma unroll
    for (int rt = 0; rt < 2; rt++)
#pragma unroll
        for (int nt = 0; nt < 8; nt++) acc[rt][nt] = {0.f, 0.f, 0.f, 0.f};

#pragma unroll
    for (int kt = 0; kt < 4; kt++) {
        float s8[8], h8[8];
#pragma unroll
        for (int t = 0; t < 8; t++) {
            s8[t] = sscale[kt * 32 + quad * 8 + t];
            h8[t] = sshift[kt * 32 + quad * 8 + t];
        }
        bf16x8 af[2];
#pragma unroll
        for (int rt = 0; rt < 2; rt++) {
            u32 w4[4] = {ra[rt][kt].x, ra[rt][kt].y, ra[rt][kt].z, ra[rt][kt].w};
            bf16x8 tmp;
#pragma unroll
            for (int t = 0; t < 4; t++) {
                float2 f = bfx2(w4[t]);
                f.x = fmaxf(fmaf(f.x, s8[2 * t], h8[2 * t]), 0.f);
                f.y = fmaxf(fmaf(f.y, s8[2 * t + 1], h8[2 * t + 1]), 0.f);
                tmp[2 * t] = (short)f2bf(f.x);
                tmp[2 * t + 1] = (short)f2bf(f.y);
            }
            af[rt] = tmp;
        }
#pragma unroll
        for (int nt = 0; nt < 8; nt++) {
            bf16x8 bf = *(const bf16x8*)&Wl[(nt * 16 + l15) * KP + kt * 32 + quad * 8];
            acc[0][nt] = __builtin_amdgcn_mfma_f32_16x16x32_bf16(af[0], bf, acc[0][nt], 0, 0, 0);
            acc[1][nt] = __builtin_amdgcn_mfma_f32_16x16x32_bf16(af[1], bf, acc[1][nt], 0, 0, 0);
        }
    }

    float b[8];
#pragma unroll
    for (int nt = 0; nt < 8; nt++) b[nt] = bf2f(bias[nt * 16 + l15]);
    float cur[8];
#pragma unroll
    for (int nt = 0; nt < 8; nt++) cur[nt] = 0.f;
    int curg = -1;
#pragma unroll
    for (int rt = 0; rt < 2; rt++)
#pragma unroll
        for (int i = 0; i < 4; i++) {
            int r = row0 + rt * 16 + quad * 4 + i;
            if (r < M) {
                int g = batch[r];
                if (g != curg) {
                    if (curg >= 0) {
#pragma unroll
                        for (int nt = 0; nt < 8; nt++)
                            if (cur[nt] > 0.f) {
                                u32 bits = __float_as_uint(cur[nt]);
                                if (fast)
                                    atomicMax(&lmax[(curg - gfirst) * 128 + nt * 16 + l15], bits);
                                else
                                    atomicMax(&pooled[curg * 128 + nt * 16 + l15], bits);
                            }
                    }
                    curg = g;
#pragma unroll
                    for (int nt = 0; nt < 8; nt++) cur[nt] = 0.f;
                }
#pragma unroll
                for (int nt = 0; nt < 8; nt++)
                    cur[nt] = fmaxf(cur[nt], fmaxf(acc[rt][nt][i] + b[nt], 0.f));
            }
        }
    if (curg >= 0) {
#pragma unroll
        for (int nt = 0; nt < 8; nt++)
            if (cur[nt] > 0.f) {
                u32 bits = __float_as_uint(cur[nt]);
                if (fast)
                    atomicMax(&lmax[(curg - gfirst) * 128 + nt * 16 + l15], bits);
                else
                    atomicMax(&pooled[curg * 128 + nt * 16 + l15], bits);
            }
    }
    __syncthreads();
    if (fast) {
        int ngr = glast - gfirst + 1;
        for (int i = tid; i < ngr * 128; i += 256) {
            u32 v = lmax[i];
            if (v) atomicMax(&pooled[gfirst * 128 + i], v);
        }
    }
}

// ---------- head part 1: zf[64,64] = pooled[64,128] @ W5 + b5 ----------
__global__ __launch_bounds__(256) void head1_kernel(const u32* __restrict__ pooled,
                                                    const u16* __restrict__ W5,
                                                    const u16* __restrict__ b5,
                                                    float* __restrict__ zf) {
    __shared__ float red[4][64];
    int g = blockIdx.x;
    int c = threadIdx.x & 63;
    int kq = threadIdx.x >> 6;
    const u32* prow = pooled + g * 128;
    float p = 0.f;
    for (int k = kq * 32; k < kq * 32 + 32; k++)
        p = fmaf(__uint_as_float(prow[k]), bf2f(W5[k * 64 + c]), p);
    red[kq][c] = p;
    __syncthreads();
    if (kq == 0) zf[g * 64 + c] = red[0][c] + red[1][c] + red[2][c] + red[3][c] + bf2f(b5[c]);
}

// ---------- head part 2 ----------
__global__ __launch_bounds__(64) void head2_kernel(const float* __restrict__ zf,
                                                   const u16* __restrict__ g2,
                                                   const u16* __restrict__ be2,
                                                   const u16* __restrict__ W6,
                                                   const u16* __restrict__ b6,
                                                   void* __restrict__ outv,
                                                   const int* __restrict__ flag) {
    __shared__ float Z[64][65];
    __shared__ float sc[64], sh[64], w6[64];
    int t = threadIdx.x;
    for (int idx = t; idx < 4096; idx += 64) Z[idx >> 6][idx & 63] = zf[idx];
    w6[t] = bf2f(W6[t]);
    __syncthreads();
    {
        float s = 0.f, sq = 0.f;
        for (int g = 0; g < 64; g++) {
            float v = Z[g][t];
            s += v;
            sq += v * v;
        }
        float mu = s * (1.f / 64.f);
        float var = sq * (1.f / 64.f) - mu * mu;
        float rstd = rsqrtf(var + EPS);
        float scale = rstd * bf2f(g2[t]);
        sc[t] = scale;
        sh[t] = bf2f(be2[t]) - mu * scale;
    }
    __syncthreads();
    float o = 0.f;
    for (int c = 0; c < 64; c++)
        o = fmaf(fmaxf(fmaf(Z[t][c], sc[c], sh[c]), 0.f), w6[c], o);
    float res = o + bf2f(b6[0]);
    if (*flag)
        ((u16*)outv)[t] = f2bf(res);
    else
        ((float*)outv)[t] = res;
}

extern "C" void kernel_launch(void* const* d_in, const int* in_sizes, int n_in, void* d_out,
                              int out_size, void* d_ws, size_t ws_size, hipStream_t stream) {
    const void* x = d_in[0];
    const int* ei = (const int*)d_in[1];
    const int* bat = (const int*)d_in[2];

    char* ws = (char*)d_ws;
    int* counts = (int*)(ws + WS_COUNTS);
    int* cursor = (int*)(ws + WS_CURSOR);
    u32* pooled = (u32*)(ws + WS_POOLED);
    float* bnsum = (float*)(ws + WS_BNSUM);
    float* bnssq = (float*)(ws + WS_BNSUMSQ);
    int* flag = (int*)(ws + WS_FLAG);
    int* offs = (int*)(ws + WS_OFFSETS);
    float* dinv = (float*)(ws + WS_DINV);
    int* partials = (int*)(ws + WS_DINV2);
    int* srcs = (int*)(ws + WS_SRCS);
    float* zf = (float*)(ws + WS_ZF);
    u16* cw = (u16*)(ws + WS_CANONW);
    u16* P2 = (u16*)(ws + WS_BUFA);             // plane-major hs2 [8][N][16]
    u16* xs4 = (u16*)(ws + WS_BUFB);            // plane-major xs [4][N][8] (dead after agg1)
    u16* axs = (u16*)(ws + WS_BUFB) + 3200000;  // [N][32] at BUFB+6.4MB (dead after gemmx)
    u16* x2p = (u16*)(ws + WS_BUFB);            // plane-major x2/y3 [8][N][16], in-place reuse

    const int* esrc = ei;
    const int* edst = ei + N_EDGES;

    hipMemsetAsync(ws, 0, ZERO_BYTES, stream);
    detect_kernel<<<1, 256, 0, stream>>>((const u32*)x, flag);

    SmallArgs sa;
    const int cw_off[16] = {CW_W1, CW_B1, CW_W2, CW_B2, CW_W3, CW_B3, CW_G1, CW_BE1,
                            CW_W4, CW_B4, CW_W5, CW_B5, CW_G2, CW_BE2, CW_W6, CW_B6};
    const int cw_n[16] = {4096, 128, 16384, 128, 16384, 128, 128, 128,
                          16384, 128, 8192, 64, 64, 64, 64, 1};
    const int cw_c[16] = {128, 0, 128, 0, 128, 0, 0, 0, 128, 0, 0, 0, 0, 0, 0, 0};
    for (int j = 0; j < 16; j++) {
        sa.src[j] = d_in[3 + j];
        sa.n[j] = cw_n[j];
        sa.off[j] = cw_off[j];
        sa.cols[j] = cw_c[j];
    }
    convs_kernel<<<64, 256, 0, stream>>>(sa, cw, flag);

    deg_kernel<<<(N_EDGES + 255) / 256, 256, 0, stream>>>(edst, counts);
    reduce_kernel<<<SCAN_BLOCKS, 256, 0, stream>>>(counts, partials);
    scanpart_kernel<<<1, 512, 0, stream>>>(partials);
    offsets_kernel<<<SCAN_BLOCKS, 256, 0, stream>>>(counts, partials, offs, dinv);
    // merged scatter + convx (both depend only on offsets)
    scatconv_kernel<<<SCAT_BLOCKS + (N_NODES * 32 + 255) / 256, 256, 0, stream>>>(
        esrc, edst, offs, cursor, srcs, x, xs4, flag, dinv);

    const int gb = (N_NODES + 127) / 128;
    // agg1: axs = aggnorm(xs) (XCD-sliced gather, K=32)
    agg1_kernel<<<4 * SCAN_BLOCKS, 256, 0, stream>>>(xs4, offs, srcs, dinv, axs);
    // gemmx: x1 = relu(axs@W1 + b1); hs2 = (x1@W2)*dinv -> P2 plane-major
    gemmx_kernel<<<gb, 256, 0, stream>>>(axs, cw + CW_W1, cw + CW_B1, cw + CW_W2, P2, dinv,
                                         N_NODES);
    // agg2: x2 = relu((agg hs2 + hs2)*dinv + b2) (XCD-sliced gather) -> x2p plane-major
    agg2_kernel<<<8 * gb, 256, 0, stream>>>(P2, offs, srcs, dinv, cw + CW_B2, x2p);
    // gemm3: y3 = x2 @ W3 + b3 (+BN stats) -> in place over x2p (block-local alias, safe)
    gemm3_kernel<<<gb, 256, 0, stream>>>(x2p, cw + CW_W3, cw + CW_B3, x2p, bnsum, bnssq,
                                         N_NODES);
    // gemm4 (bnstats folded in): relu(relu(BN(y3)) @ W4 + b4) -> segment max into pooled
    gemm4_kernel<<<gb, 256, 0, stream>>>(x2p, cw + CW_W4, cw + CW_B4, bnsum, bnssq, cw + CW_G1,
                                         cw + CW_BE1, bat, pooled, N_NODES);
    // head
    head1_kernel<<<N_GRAPHS, 256, 0, stream>>>(pooled, cw + CW_W5, cw + CW_B5, zf);
    head2_kernel<<<1, 64, 0, stream>>>(zf, cw + CW_G2, cw + CW_BE2, cw + CW_W6, cw + CW_B6,
                                       d_out, flag);
}